// Round 20
// baseline (381.705 us; speedup 1.0000x reference)
//
#include <hip/hip_runtime.h>
#include <hip/hip_fp16.h>
#include <math.h>

constexpr int BT = 65536;
constexpr int D  = 256;
constexpr int E  = 64;
constexpr int K  = 2048;
constexpr int J  = 512; // 2*D

// d_out layout (floats): res | topk_idx | topk_scores | counts
constexpr size_t OFF_IDX = (size_t)BT * D * 2;       // 33,554,432
constexpr size_t OFF_SCR = OFF_IDX + (size_t)E * K;  // +131,072
constexpr size_t OFF_CNT = OFF_SCR + (size_t)E * K;  // +131,072

// d_ws layout (bytes):
//   xb   bf16[BT][512]        @ 0          (64 MiB)
//   bm   bf16[E][512][512]    @ 64 MiB     (32 MiB)
//   yD   fp16[E*K][512]       @ 96 MiB     (128 MiB)   [tier-1 only]
//   cur  int[BT]              @ 224 MiB    (256 KiB)   [tier-1 only]
//   slot int[BT][32]          @ 224.25 MiB (8 MiB)     [tier-1 only]
constexpr size_t WS_XB    = 0;
constexpr size_t WS_BM    = 67108864;
constexpr size_t WS_YD    = 100663296;
constexpr size_t WS_CUR   = 234881024;
constexpr size_t WS_SLOT  = 235143168;
constexpr size_t WS_NEED1 = 243531776;              // tier-1: full path
constexpr size_t WS_NEED2 = 100663296;              // tier-2 path
constexpr int    SLOT_PAD = 32;

typedef __attribute__((ext_vector_type(8))) short bf16x8;
typedef __attribute__((ext_vector_type(4))) float f32x4;
typedef __attribute__((ext_vector_type(4))) unsigned int u32x4;

__device__ __forceinline__ unsigned short f2bf(float f) {
  unsigned u = __float_as_uint(f);
  u = (u + 0x7FFFu + ((u >> 16) & 1u)) >> 16;  // RTNE
  return (unsigned short)u;
}

__device__ __forceinline__ void gl16(const void* g, void* l) {
  __builtin_amdgcn_global_load_lds(
      (const __attribute__((address_space(1))) unsigned int*)g,
      (__attribute__((address_space(3))) unsigned int*)l, 16, 0, 0);
}

__device__ __forceinline__ unsigned fkey(float s) {
  unsigned u = __float_as_uint(s);
  return (u & 0x80000000u) ? ~u : (u | 0x80000000u);
}

// ---------------------------------------------------------------------------
// K1 (v2 + NT x-loads): scoresT[e][t] = fp32 dot as ONE sequential FMA chain
// j=0..511 (bit-matches np's sgemm scheme — chain order UNCHANGED).
// b128 LDS reads. NT loads keep the 128 MB read-once x stream out of L2 so
// the scoresT stores stay resident for k2a/k2c. Fused: emits xb = bf16(x).
// ---------------------------------------------------------------------------
__global__ __launch_bounds__(256)
void k1_scores(const float* __restrict__ x, const float* __restrict__ gw,
               float* __restrict__ scoresT, unsigned short* __restrict__ xbp) {
  __shared__ float xs[128][68];   // 34.8 KB
  __shared__ float gsT[64][68];   // 17.4 KB
  const int t0 = blockIdx.x * 128;
  const int tid = threadIdx.x;
  const int tx = tid & 15;   // token sub-index (8 tokens: a*16+tx)
  const int ty = tid >> 4;   // expert group (4 experts: ty*4+b)
  float acc[8][4] = {};

  for (int kk = 0; kk < 8; ++kk) {
    // ---- stage x (float4 coalesced, NT) + fused bf16 emit
#pragma unroll
    for (int i = 0; i < 8; ++i) {
      int idx = tid + 256 * i;
      int r = idx >> 4, c4 = (idx & 15) * 4;
      f32x4 v = __builtin_nontemporal_load(
          (const f32x4*)(&x[(size_t)(t0 + r) * J + kk * 64 + c4]));
      *(f32x4*)(&xs[r][c4]) = v;
      if (xbp) {
        uint2 u;
        u.x = (unsigned)f2bf(v.x) | ((unsigned)f2bf(v.y) << 16);
        u.y = (unsigned)f2bf(v.z) | ((unsigned)f2bf(v.w) << 16);
        *(uint2*)(&xbp[(size_t)(t0 + r) * J + kk * 64 + c4]) = u;
      }
    }
    // ---- stage gw transposed: gsT[e][j]
#pragma unroll
    for (int i = 0; i < 4; ++i) {
      int idx = tid + 256 * i;
      int r = idx >> 4, c4 = (idx & 15) * 4;   // r = j-local, c4 = expert
      float4 v = *(const float4*)(&gw[(size_t)(kk * 64 + r) * E + c4]);
      gsT[c4][r]     = v.x;
      gsT[c4 + 1][r] = v.y;
      gsT[c4 + 2][r] = v.z;
      gsT[c4 + 3][r] = v.w;
    }
    __syncthreads();
    // ---- compute: j in groups of 4, b128 reads, chain order preserved
#pragma unroll 4
    for (int j = 0; j < 64; j += 4) {
      float4 xv[8], gv[4];
#pragma unroll
      for (int a = 0; a < 8; ++a)
        xv[a] = *(const float4*)(&xs[a * 16 + tx][j]);
#pragma unroll
      for (int b = 0; b < 4; ++b)
        gv[b] = *(const float4*)(&gsT[ty * 4 + b][j]);
#define K1_FMA(COMP)                                                        \
  _Pragma("unroll") for (int a = 0; a < 8; ++a)                             \
    _Pragma("unroll") for (int b = 0; b < 4; ++b)                           \
      acc[a][b] = fmaf(xv[a].COMP, gv[b].COMP, acc[a][b]);
      K1_FMA(x) K1_FMA(y) K1_FMA(z) K1_FMA(w)
#undef K1_FMA
    }
    __syncthreads();
  }

#pragma unroll
  for (int b = 0; b < 4; ++b) {
    int e = ty * 4 + b;
#pragma unroll
    for (int a = 0; a < 8; ++a)
      scoresT[(size_t)e * BT + t0 + a * 16 + tx] = acc[a][b];
  }
}

// ---------------------------------------------------------------------------
// K2a: 12-bit-key histogram, 4 blocks/expert, 8-way privatized LDS, then a
// NON-atomic partial write to parts[bid][4096].
// Fused: zeros o_cnt and cur (256 blocks x 1024 threads == BT exactly).
// ---------------------------------------------------------------------------
__global__ __launch_bounds__(1024)
void k2a_hist(const float* __restrict__ scoresT, unsigned* __restrict__ parts,
              float* __restrict__ o_cnt, int* __restrict__ cur) {
  const int bid = blockIdx.x;          // e*4 + q
  const int tid = threadIdx.x;
  const int g   = bid * 1024 + tid;    // 0 .. BT-1
  o_cnt[g] = 0.0f;
  if (cur) cur[g] = 0;
  __shared__ unsigned h[8][4096];      // 128 KiB, 8-way privatization
  for (int i = tid; i < 8 * 4096; i += 1024) ((unsigned*)h)[i] = 0u;
  __syncthreads();
  const int copy = tid >> 7;           // 2 waves share a copy
  const float4* src = (const float4*)(scoresT + ((size_t)bid << 14));
#pragma unroll
  for (int it = 0; it < 4; ++it) {
    float4 v = src[it * 1024 + tid];
    atomicAdd(&h[copy][fkey(v.x) >> 20], 1u);
    atomicAdd(&h[copy][fkey(v.y) >> 20], 1u);
    atomicAdd(&h[copy][fkey(v.z) >> 20], 1u);
    atomicAdd(&h[copy][fkey(v.w) >> 20], 1u);
  }
  __syncthreads();
  unsigned* dst = parts + ((size_t)bid << 12);
  for (int j = tid; j < 4096; j += 1024) {
    unsigned s = 0;
#pragma unroll
    for (int c = 0; c < 8; ++c) s += h[c][j];
    dst[j] = s;
  }
}

// ---------------------------------------------------------------------------
// K2b: per-expert descending scan over summed parts -> 12-bit bucket of the
// rank-K key. Fused: zeros ccnt[e].
// ---------------------------------------------------------------------------
__global__ __launch_bounds__(256)
void k2b_scan(const unsigned* __restrict__ parts, unsigned* __restrict__ thr12,
              int* __restrict__ ccnt) {
  const int e = blockIdx.x;
  const unsigned* p = parts + ((size_t)e << 14);  // 4 parts x 4096
  __shared__ unsigned chs[256];
  const int tid = threadIdx.x;
  if (tid == 0) ccnt[e] = 0;
  const int lo = 4095 - tid * 16 - 15;  // chunk tid covers [lo, lo+15] desc
  unsigned s = 0;
  for (int j = 0; j < 16; ++j) {
    int b = lo + j;
    s += p[b] + p[4096 + b] + p[8192 + b] + p[12288 + b];
  }
  chs[tid] = s;
  __syncthreads();
  if (tid == 0) {
    unsigned cum = 0; int c = 0;
    for (; c < 255; ++c) {
      if (cum + chs[c] >= (unsigned)K) break;
      cum += chs[c];
    }
    int vb = 4095 - c * 16;
    unsigned b = 0;
    for (int j = 0; j < 16; ++j) {
      int bb = vb - j;
      cum += p[bb] + p[4096 + bb] + p[8192 + bb] + p[12288 + bb];
      if (cum >= (unsigned)K) { b = (unsigned)bb; break; }
    }
    thr12[e] = b;
  }
}

// ---------------------------------------------------------------------------
// K2c: parallel collect, 4 blocks/expert. LDS-local cursor; ONE global
// atomic per block reserves a segment of cand[e]; coalesced flush.
// NT loads: k2c is the LAST reader of scoresT.
// ---------------------------------------------------------------------------
__global__ __launch_bounds__(1024)
void k2c_collect(const float* __restrict__ scoresT,
                 const unsigned* __restrict__ thr12,
                 unsigned long long* __restrict__ cand,
                 int* __restrict__ ccnt) {
  const int bid = blockIdx.x;  // e*4 + q
  const int e = bid >> 2;
  const unsigned bthr = thr12[e] << 20;
  const float* row = scoresT + ((size_t)bid << 14);
  const unsigned ibase = (unsigned)(bid & 3) << 14;
  __shared__ int sh_n, sh_base;
  __shared__ unsigned long long lkeys[4096];
  const int tid = threadIdx.x;
  if (tid == 0) sh_n = 0;
  __syncthreads();
  for (int i = tid; i < 16384; i += 1024) {
    float sv = __builtin_nontemporal_load(&row[i]);
    unsigned u = fkey(sv);
    if (u >= bthr) {
      int pos = atomicAdd(&sh_n, 1);   // LDS atomic
      if (pos < 4096)
        lkeys[pos] =
            ((unsigned long long)u << 32) | (unsigned)(~(ibase + i));
    }
  }
  __syncthreads();
  int n = sh_n; if (n > 4096) n = 4096;
  if (tid == 0) sh_base = atomicAdd(&ccnt[e], n);  // one global atomic/block
  __syncthreads();
  const int base = sh_base;
  for (int i = tid; i < n; i += 1024)
    if (base + i < 4096) cand[((size_t)e << 12) + base + i] = lkeys[i];
}

// ---------------------------------------------------------------------------
// K2d: per-expert bitonic sort of candidates (score desc, idx asc) + output
// tail. Comparator network is order-canonical -> bit-identical results.
// NT loads for cand (read-once).
// ---------------------------------------------------------------------------
__global__ __launch_bounds__(1024)
void k2d_sort(const unsigned long long* __restrict__ cand,
              const int* __restrict__ ccnt,
              float* __restrict__ o_idx, float* __restrict__ o_scr,
              float* __restrict__ o_cnt,
              int* __restrict__ cur, int* __restrict__ slots) {
  const int e = blockIdx.x;
  __shared__ unsigned long long keys[4096];
  const int tid = threadIdx.x;
  int n = ccnt[e]; if (n > 4096) n = 4096;
  for (int i = tid; i < 4096; i += 1024)
    keys[i] = (i < n)
        ? __builtin_nontemporal_load(&cand[((size_t)e << 12) + i])
        : 0ull;
  __syncthreads();
  for (int kk = 2; kk <= 4096; kk <<= 1) {
    for (int j = kk >> 1; j > 0; j >>= 1) {
      for (int i = tid; i < 4096; i += 1024) {
        int ij = i ^ j;
        if (ij > i) {
          bool up = ((i & kk) == 0);
          unsigned long long a = keys[i], b = keys[ij];
          if ((a < b) == up) { keys[i] = b; keys[ij] = a; }
        }
      }
      __syncthreads();
    }
  }
  for (int r = tid; r < K; r += 1024) {
    unsigned long long kv = keys[r];
    unsigned u = (unsigned)(kv >> 32);
    unsigned idx = ~((unsigned)kv);
    float s = __uint_as_float((u & 0x80000000u) ? (u ^ 0x80000000u) : ~u);
    o_idx[(size_t)e * K + r] = (float)idx;
    o_scr[(size_t)e * K + r] = s;
    atomicAdd(&o_cnt[idx], 1.0f);
    if (slots) {
      int pos = atomicAdd(&cur[idx], 1);
      if (pos < SLOT_PAD) slots[(size_t)idx * SLOT_PAD + pos] = e * K + r;
    }
  }
}

// ---------------------------------------------------------------------------
// K3b: Bmat[e][n=2f+co][k=2d+ci] = bf16( ew[e][d][f][ci^co] * sign ).
// ---------------------------------------------------------------------------
__global__ __launch_bounds__(256)
void k3b_bmat(const float* __restrict__ ew, unsigned short* __restrict__ bm) {
  int id = blockIdx.x * 256 + threadIdx.x;
  int sub = id & 63;
  int ng  = id >> 6;
  int e   = ng >> 9;
  int n   = ng & 511;
  int f   = n >> 1, co = n & 1;
  int d0  = sub * 4;
  const float* wb = ew + (((size_t)e * 256) * 256 + f) * 2;
  union { unsigned short h[8]; bf16x8 v; } pk;
#pragma unroll
  for (int dd = 0; dd < 4; ++dd) {
    float2 wv = *(const float2*)(wb + (size_t)(d0 + dd) * 512);
    float b0 = co ? wv.y : wv.x;
    float b1 = co ? wv.x : -wv.y;
    pk.h[dd * 2]     = f2bf(b0);
    pk.h[dd * 2 + 1] = f2bf(b1);
  }
  ((bf16x8*)bm)[id] = pk.v;
}

// ---------------------------------------------------------------------------
// K4c (tier-1, v8): MFMA bf16 GEMM, dense fp16 output (NO atomics).
// 128x128 tile, BK=64, 2-phase double-buffered LDS, setprio(1) around MFMA
// cluster (T5, +13% measured), NT yD stores (write-once stream).
// ---------------------------------------------------------------------------
__global__ __launch_bounds__(256)
void k4c_mfma(const unsigned short* __restrict__ xb,
              const unsigned short* __restrict__ bm,
              const float* __restrict__ o_idx, const float* __restrict__ o_scr,
              unsigned short* __restrict__ yD) {
  const int bid = blockIdx.x;
  const int xcd = bid & 7;
  const int s   = bid >> 3;
  const int fn  = s & 3;
  const int km  = (s >> 2) & 15;
  const int e   = xcd + ((s >> 6) << 3);

  // sh: A dbuf = sh + cb*8192 (each 128 rows x 64 shorts);
  //     B dbuf = sh + 16384 + cb*8192. Pk overlay @0 (17408 shorts).
  __shared__ __align__(16) unsigned short sh[32768];
  __shared__ int   tIdx[128];
  __shared__ float wRow[128];
  const int tid = threadIdx.x;
  if (tid < 128) {
    size_t gi = (size_t)e * K + km * 128 + tid;
    tIdx[tid] = (int)o_idx[gi];
    wRow[tid] = o_scr[gi];
  }
  __syncthreads();

  const int lane = tid & 63;
  const int w    = tid >> 6;
  const int wr   = (w & 1) * 64;
  const int wc   = (w >> 1) * 64;
  const int l15  = lane & 15, l4 = lane >> 4;
  const int ls   = lane & 7, lr = lane >> 3;
  const int gch  = ls ^ lr;  // pre-swizzled source chunk (row&7 == lr)

  // per-lane global source bases and LDS dest offsets (shorts) per row-octet
  const char* aSrc[4];
  const char* bSrc[4];
  int dstOff[4];
#pragma unroll
  for (int i = 0; i < 4; ++i) {
    int r = w * 32 + i * 8 + lr;
    aSrc[i] = (const char*)xb + (size_t)tIdx[r] * 1024 + gch * 16;
    bSrc[i] = (const char*)bm + ((size_t)e * 512 + fn * 128 + r) * 1024 +
              gch * 16;
    dstOff[i] = (w * 32 + i * 8) * 64 + lane * 8;
  }

  f32x4 acc[4][4];
#pragma unroll
  for (int m = 0; m < 4; ++m)
#pragma unroll
    for (int n = 0; n < 4; ++n) acc[m][n] = (f32x4){0.f, 0.f, 0.f, 0.f};

  // prologue: K-step 0 into buffer 0
#pragma unroll
  for (int i = 0; i < 4; ++i) {
    gl16(aSrc[i], sh + dstOff[i]);
    gl16(bSrc[i], sh + 16384 + dstOff[i]);
  }

#pragma unroll
  for (int t = 0; t < 8; ++t) {
    const int cb = t & 1;
    __syncthreads();  // drains vmcnt -> buffer cb ready
    if (t < 7) {      // stage next tile into cb^1 while computing cb
      const int nxt = (cb ^ 1) * 8192;
#pragma unroll
      for (int i = 0; i < 4; ++i) {
        gl16(aSrc[i] + (t + 1) * 128, sh + nxt + dstOff[i]);
        gl16(bSrc[i] + (t + 1) * 128, sh + 16384 + nxt + dstOff[i]);
      }
    }
    const unsigned short* Ab = sh + cb * 8192;
    const unsigned short* Bb = sh + 16384 + cb * 8192;
#pragma unroll
    for (int kk2 = 0; kk2 < 2; ++kk2) {
      bf16x8 af[4], bfr[4];
#pragma unroll
      for (int m = 0; m < 4; ++m) {
        int r = wr + m * 16 + l15;
        int sw = (kk2 * 4 + l4) ^ (r & 7);
        af[m] = *(const bf16x8*)(&Ab[r * 64 + sw * 8]);
      }
#pragma unroll
      for (int n = 0; n < 4; ++n) {
        int cl = wc + n * 16 + l15;
        int sw = (kk2 * 4 + l4) ^ (cl & 7);
        bfr[n] = *(const bf16x8*)(&Bb[cl * 64 + sw * 8]);
      }
      __builtin_amdgcn_s_setprio(1);
#pragma unroll
      for (int m = 0; m < 4; ++m)
#pragma unroll
        for (int n = 0; n < 4; ++n)
          acc[m][n] = __builtin_amdgcn_mfma_f32_16x16x32_bf16(
              af[m], bfr[n], acc[m][n], 0, 0, 0);
      __builtin_amdgcn_s_setprio(0);
    }
  }

  // epilogue: weight, fp16-pack via padded-LDS repack (stride 136), NT store
  __syncthreads();
  unsigned short* Pk = sh;  // 128 x 136 = 17408 shorts (fits in 32768)
#pragma unroll
  for (int m = 0; m < 4; ++m) {
#pragma unroll
    for (int q = 0; q < 4; ++q) {
      int row = wr + m * 16 + l4 * 4 + q;
      float wv = wRow[row];
#pragma unroll
      for (int n = 0; n < 4; ++n) {
        int col = wc + n * 16 + l15;
        Pk[row * 136 + col] =
            __half_as_ushort(__float2half(acc[m][n][q] * wv));
      }
    }
  }
  __syncthreads();
  const size_t rowBase = (size_t)e * K + km * 128;
#pragma unroll
  for (int i = 0; i < 8; ++i) {
    int c2 = tid + 256 * i;
    int row = c2 >> 4, ch = c2 & 15;
    u32x4 v = *(const u32x4*)(&Pk[row * 136 + ch * 8]);
    __builtin_nontemporal_store(
        v, (u32x4*)(yD + (rowBase + row) * 512 + fn * 128 + ch * 8));
  }
}

// ---------------------------------------------------------------------------
// K5g (tier-1): per-token gather-finalize (one wave per token).
// NT loads for yD (read-once) and NT stores for res (write-once).
// ---------------------------------------------------------------------------
__global__ __launch_bounds__(256)
void k5g(const unsigned short* __restrict__ yD, const int* __restrict__ cur,
         const int* __restrict__ slots, const float* __restrict__ bias,
         float* __restrict__ res) {
  const int t    = blockIdx.x * 4 + (threadIdx.x >> 6);
  const int lane = threadIdx.x & 63;
  const int nc   = cur[t];
  const int ncc  = nc < SLOT_PAD ? nc : SLOT_PAD;
  float acc[8] = {};
  const int* sl = slots + (size_t)t * SLOT_PAD;
  for (int c = 0; c < ncc; ++c) {
    int slot = sl[c];
    union { u32x4 v; unsigned short h[8]; } U;
    U.v = __builtin_nontemporal_load(
        (const u32x4*)(yD + (size_t)slot * 512 + lane * 8));
#pragma unroll
    for (int j = 0; j < 8; ++j)
      acc[j] += __half2float(__ushort_as_half(U.h[j]));
  }
  const float inv = 1.0f / fmaxf((float)nc, 1.0f);
  float4 b4 = *(const float4*)(bias + lane * 4);
  const float* bp = (const float*)&b4;
  const float is2 = 0.70710678118654752f;
  float r8[8];
#pragma unroll
  for (int j = 0; j < 8; ++j) {
    float h = acc[j] * inv + bp[j >> 1];
    r8[j] = 0.5f * h * (1.0f + erff(h * is2));
  }
  float* dst = res + (size_t)t * J + lane * 8;
  f32x4 lo = (f32x4){r8[0], r8[1], r8[2], r8[3]};
  f32x4 hi = (f32x4){r8[4], r8[5], r8[6], r8[7]};
  __builtin_nontemporal_store(lo, (f32x4*)dst);
  __builtin_nontemporal_store(hi, (f32x4*)(dst + 4));
}

// ---------------------------------------------------------------------------
// K4b (tier-2 fallback): atomic-scatter MFMA GEMM (round-7 verified).
// ---------------------------------------------------------------------------
__global__ __launch_bounds__(256)
void k4b_mfma(const unsigned short* __restrict__ xb,
              const unsigned short* __restrict__ bm,
              const float* __restrict__ o_idx, const float* __restrict__ o_scr,
              float* __restrict__ out) {
  const int e  = blockIdx.z;
  const int km = blockIdx.y;
  const int fn = blockIdx.x;
  __shared__ __align__(16) unsigned short As[128 * 64];
  __shared__ __align__(16) unsigned short Bs[128 * 64];
  __shared__ int   tIdx[128];
  __shared__ float wRow[128];
  const int tid = threadIdx.x;
  if (tid < 128) {
    size_t gi = (size_t)e * K + km * 128 + tid;
    tIdx[tid] = (int)o_idx[gi];
    wRow[tid] = o_scr[gi];
  }
  __syncthreads();

  const int lane = tid & 63;
  const int w    = tid >> 6;
  const int wr   = (w & 1) * 64;
  const int wc   = (w >> 1) * 64;
  const int l15  = lane & 15, l4 = lane >> 4;
  const int ls   = lane & 7, lr = lane >> 3;
  const int gch  = ls ^ lr;

  const char* aSrc[4];
  const char* bSrc[4];
  unsigned short* aDst[4];
  unsigned short* bDst[4];
#pragma unroll
  for (int i = 0; i < 4; ++i) {
    int r = w * 32 + i * 8 + lr;
    aSrc[i] = (const char*)xb + (size_t)tIdx[r] * 1024 + gch * 16;
    bSrc[i] = (const char*)bm + ((size_t)e * 512 + fn * 128 + r) * 1024 +
              gch * 16;
    aDst[i] = As + (w * 32 + i * 8) * 64 + lane * 8;
    bDst[i] = Bs + (w * 32 + i * 8) * 64 + lane * 8;
  }

  f32x4 acc[4][4];
#pragma unroll
  for (int m = 0; m < 4; ++m)
#pragma unroll
    for (int n = 0; n < 4; ++n) acc[m][n] = (f32x4){0.f, 0.f, 0.f, 0.f};

  for (int kk = 0; kk < J; kk += 64) {
#pragma unroll
    for (int i = 0; i < 4; ++i) {
      gl16(aSrc[i] + kk * 2, aDst[i]);
      gl16(bSrc[i] + kk * 2, bDst[i]);
    }
    __syncthreads();
#pragma unroll
    for (int kk2 = 0; kk2 < 2; ++kk2) {
      bf16x8 af[4], bfr[4];
#pragma unroll
      for (int m = 0; m < 4; ++m) {
        int r = wr + m * 16 + l15;
        int s = (kk2 * 4 + l4) ^ (r & 7);
        af[m] = *(const bf16x8*)(&As[r * 64 + s * 8]);
      }
#pragma unroll
      for (int n = 0; n < 4; ++n) {
        int cl = wc + n * 16 + l15;
        int s = (kk2 * 4 + l4) ^ (cl & 7);
        bfr[n] = *(const bf16x8*)(&Bs[cl * 64 + s * 8]);
      }
#pragma unroll
      for (int m = 0; m < 4; ++m)
#pragma unroll
        for (int n = 0; n < 4; ++n)
          acc[m][n] = __builtin_amdgcn_mfma_f32_16x16x32_bf16(
              af[m], bfr[n], acc[m][n], 0, 0, 0);
    }
    __syncthreads();
  }

#pragma unroll
  for (int m = 0; m < 4; ++m) {
#pragma unroll
    for (int q = 0; q < 4; ++q) {
      int rl = wr + m * 16 + l4 * 4 + q;
      int t = tIdx[rl];
      float wv = wRow[rl];
      float* dst = out + (size_t)t * J + fn * 128 + wc + l15;
#pragma unroll
      for (int n = 0; n < 4; ++n)
        atomicAdd(dst + n * 16, acc[m][n][q] * wv);
    }
  }
}

// ---------------------------------------------------------------------------
// K5 (tier-2 fallback): res = gelu(out/max(cnt,1)+bias), in place.
// ---------------------------------------------------------------------------
__global__ __launch_bounds__(256)
void k5_final(float* __restrict__ res, const float* __restrict__ cnt,
              const float* __restrict__ bias) {
  const int total4 = BT * J / 4;
  for (int i = blockIdx.x * blockDim.x + threadIdx.x; i < total4;
       i += gridDim.x * blockDim.x) {
    float4 v = reinterpret_cast<float4*>(res)[i];
    int base = i << 2;
    int t = base >> 9;
    int col = base & 511;
    float inv = 1.0f / fmaxf(cnt[t], 1.0f);
    int f0 = col >> 1;
    float b0 = bias[f0], b1 = bias[f0 + 1];
    float h0 = v.x * inv + b0;
    float h1 = v.y * inv + b0;
    float h2 = v.z * inv + b1;
    float h3 = v.w * inv + b1;
    const float is2 = 0.70710678118654752f;
    v.x = 0.5f * h0 * (1.0f + erff(h0 * is2));
    v.y = 0.5f * h1 * (1.0f + erff(h1 * is2));
    v.z = 0.5f * h2 * (1.0f + erff(h2 * is2));
    v.w = 0.5f * h3 * (1.0f + erff(h3 * is2));
    reinterpret_cast<float4*>(res)[i] = v;
  }
}

// ---------------------------------------------------------------------------
extern "C" void kernel_launch(void* const* d_in, const int* in_sizes, int n_in,
                              void* d_out, int out_size, void* d_ws,
                              size_t ws_size, hipStream_t stream) {
  const float* x    = (const float*)d_in[0];
  const float* gw   = (const float*)d_in[1];
  const float* ew   = (const float*)d_in[2];
  const float* bias = (const float*)d_in[3];

  float* out_f = (float*)d_out;
  float* res   = out_f;
  float* o_idx = out_f + OFF_IDX;
  float* o_scr = out_f + OFF_SCR;
  float* o_cnt = out_f + OFF_CNT;

  // Borrowed regions inside res (all rewritten later by k5g/k5):
  //   scoresT @ 0 (16.8 MB) | parts @ 32 MB | thr12 @ 36 MB |
  //   cand @ 48 MB (2 MB) | ccnt @ 52 MB
  float*              scoresT = res;
  unsigned*           parts   = (unsigned*)((char*)res + (size_t)32 * 1024 * 1024);
  unsigned*           thr12   = (unsigned*)((char*)res + (size_t)36 * 1024 * 1024);
  unsigned long long* cand    = (unsigned long long*)((char*)res + (size_t)48 * 1024 * 1024);
  int*                ccnt    = (int*)((char*)res + (size_t)52 * 1024 * 1024);

  unsigned short* xb  = (unsigned short*)((char*)d_ws + WS_XB);
  unsigned short* bm  = (unsigned short*)((char*)d_ws + WS_BM);
  unsigned short* yD  = (unsigned short*)((char*)d_ws + WS_YD);
  int*            cur = (int*)((char*)d_ws + WS_CUR);
  int*            slt = (int*)((char*)d_ws + WS_SLOT);

  const bool tier1 = (ws_size >= WS_NEED1);
  const bool tier2 = (ws_size >= WS_NEED2);

  if (tier2) k3b_bmat<<<8192, 256, 0, stream>>>(ew, bm);

  k1_scores<<<BT / 128, 256, 0, stream>>>(x, gw, scoresT,
                                          tier2 ? xb : nullptr);
  k2a_hist<<<E * 4, 1024, 0, stream>>>(scoresT, parts, o_cnt,
                                       tier1 ? cur : nullptr);
  k2b_scan<<<E, 256, 0, stream>>>(parts, thr12, ccnt);
  k2c_collect<<<E * 4, 1024, 0, stream>>>(scoresT, thr12, cand, ccnt);
  k2d_sort<<<E, 1024, 0, stream>>>(cand, ccnt, o_idx, o_scr, o_cnt,
                                   tier1 ? cur : nullptr,
                                   tier1 ? slt : nullptr);
  if (tier1) {
    k4c_mfma<<<4096, 256, 0, stream>>>(xb, bm, o_idx, o_scr, yD);
    k5g<<<BT / 4, 256, 0, stream>>>(yD, cur, slt, bias, res);
  } else if (tier2) {
    hipMemsetAsync(res, 0, (size_t)BT * J * sizeof(float), stream);
    k4b_mfma<<<dim3(4, 16, E), 256, 0, stream>>>(xb, bm, o_idx, o_scr, res);
    k5_final<<<8192, 256, 0, stream>>>(res, o_cnt, bias);
  }
}

// Round 21
// 374.930 us; speedup vs baseline: 1.0181x; 1.0181x over previous
//
#include <hip/hip_runtime.h>
#include <hip/hip_fp16.h>
#include <math.h>

constexpr int BT = 65536;
constexpr int D  = 256;
constexpr int E  = 64;
constexpr int K  = 2048;
constexpr int J  = 512; // 2*D

// d_out layout (floats): res | topk_idx | topk_scores | counts
constexpr size_t OFF_IDX = (size_t)BT * D * 2;       // 33,554,432
constexpr size_t OFF_SCR = OFF_IDX + (size_t)E * K;  // +131,072
constexpr size_t OFF_CNT = OFF_SCR + (size_t)E * K;  // +131,072

// d_ws layout (bytes):
//   xb   bf16[BT][512]        @ 0          (64 MiB)
//   bm   bf16[E][512][512]    @ 64 MiB     (32 MiB)
//   yD   fp16[E*K][512]       @ 96 MiB     (128 MiB)   [tier-1 only]
//   cur  int[BT]              @ 224 MiB    (256 KiB)   [tier-1 only]
//   slot int[BT][32]          @ 224.25 MiB (8 MiB)     [tier-1 only]
constexpr size_t WS_XB    = 0;
constexpr size_t WS_BM    = 67108864;
constexpr size_t WS_YD    = 100663296;
constexpr size_t WS_CUR   = 234881024;
constexpr size_t WS_SLOT  = 235143168;
constexpr size_t WS_NEED1 = 243531776;              // tier-1: full path
constexpr size_t WS_NEED2 = 100663296;              // tier-2 path
constexpr int    SLOT_PAD = 32;

typedef __attribute__((ext_vector_type(8))) short bf16x8;
typedef __attribute__((ext_vector_type(4))) float f32x4;
typedef __attribute__((ext_vector_type(4))) unsigned int u32x4;

__device__ __forceinline__ unsigned short f2bf(float f) {
  unsigned u = __float_as_uint(f);
  u = (u + 0x7FFFu + ((u >> 16) & 1u)) >> 16;  // RTNE
  return (unsigned short)u;
}

__device__ __forceinline__ void gl16(const void* g, void* l) {
  __builtin_amdgcn_global_load_lds(
      (const __attribute__((address_space(1))) unsigned int*)g,
      (__attribute__((address_space(3))) unsigned int*)l, 16, 0, 0);
}

__device__ __forceinline__ unsigned fkey(float s) {
  unsigned u = __float_as_uint(s);
  return (u & 0x80000000u) ? ~u : (u | 0x80000000u);
}

// ---------------------------------------------------------------------------
// K1 (v3): scoresT[e][t] = fp32 dot as ONE sequential FMA chain j=0..511
// (bit-matches np's sgemm scheme — chain order UNCHANGED).
// v3: 64-token blocks (grid 1024 = 4 blocks/CU, occupancy 2.5x of v2's
// 2-blocks/CU grid cap), thread tile 4 tok x 4 exp, LDS 34.8 KB.
// b128 LDS reads; NT x loads; fused bf16 emit (xbp != null).
// ---------------------------------------------------------------------------
__global__ __launch_bounds__(256)
void k1_scores(const float* __restrict__ x, const float* __restrict__ gw,
               float* __restrict__ scoresT, unsigned short* __restrict__ xbp) {
  __shared__ float xs[64][68];    // 17.4 KB
  __shared__ float gsT[64][68];   // 17.4 KB
  const int t0 = blockIdx.x * 64;
  const int tid = threadIdx.x;
  const int tx = tid & 15;   // token sub-index (4 tokens: a*16+tx)
  const int ty = tid >> 4;   // expert group (4 experts: ty*4+b)
  float acc[4][4] = {};

  for (int kk = 0; kk < 8; ++kk) {
    // ---- stage x (float4 coalesced, NT) + fused bf16 emit: 1024 float4
#pragma unroll
    for (int i = 0; i < 4; ++i) {
      int idx = tid + 256 * i;
      int r = idx >> 4, c4 = (idx & 15) * 4;
      f32x4 v = __builtin_nontemporal_load(
          (const f32x4*)(&x[(size_t)(t0 + r) * J + kk * 64 + c4]));
      *(f32x4*)(&xs[r][c4]) = v;
      if (xbp) {
        uint2 u;
        u.x = (unsigned)f2bf(v.x) | ((unsigned)f2bf(v.y) << 16);
        u.y = (unsigned)f2bf(v.z) | ((unsigned)f2bf(v.w) << 16);
        *(uint2*)(&xbp[(size_t)(t0 + r) * J + kk * 64 + c4]) = u;
      }
    }
    // ---- stage gw transposed: gsT[e][j]
#pragma unroll
    for (int i = 0; i < 4; ++i) {
      int idx = tid + 256 * i;
      int r = idx >> 4, c4 = (idx & 15) * 4;   // r = j-local, c4 = expert
      float4 v = *(const float4*)(&gw[(size_t)(kk * 64 + r) * E + c4]);
      gsT[c4][r]     = v.x;
      gsT[c4 + 1][r] = v.y;
      gsT[c4 + 2][r] = v.z;
      gsT[c4 + 3][r] = v.w;
    }
    __syncthreads();
    // ---- compute: j in groups of 4, b128 reads, chain order preserved
#pragma unroll 4
    for (int j = 0; j < 64; j += 4) {
      float4 xv[4], gv[4];
#pragma unroll
      for (int a = 0; a < 4; ++a)
        xv[a] = *(const float4*)(&xs[a * 16 + tx][j]);
#pragma unroll
      for (int b = 0; b < 4; ++b)
        gv[b] = *(const float4*)(&gsT[ty * 4 + b][j]);
#define K1_FMA(COMP)                                                        \
  _Pragma("unroll") for (int a = 0; a < 4; ++a)                             \
    _Pragma("unroll") for (int b = 0; b < 4; ++b)                           \
      acc[a][b] = fmaf(xv[a].COMP, gv[b].COMP, acc[a][b]);
      K1_FMA(x) K1_FMA(y) K1_FMA(z) K1_FMA(w)
#undef K1_FMA
    }
    __syncthreads();
  }

#pragma unroll
  for (int b = 0; b < 4; ++b) {
    int e = ty * 4 + b;
#pragma unroll
    for (int a = 0; a < 4; ++a)
      scoresT[(size_t)e * BT + t0 + a * 16 + tx] = acc[a][b];
  }
}

// ---------------------------------------------------------------------------
// K2a: 12-bit-key histogram, 4 blocks/expert, 8-way privatized LDS, then a
// NON-atomic partial write to parts[bid][4096].
// Fused: zeros o_cnt and cur (256 blocks x 1024 threads == BT exactly).
// ---------------------------------------------------------------------------
__global__ __launch_bounds__(1024)
void k2a_hist(const float* __restrict__ scoresT, unsigned* __restrict__ parts,
              float* __restrict__ o_cnt, int* __restrict__ cur) {
  const int bid = blockIdx.x;          // e*4 + q
  const int tid = threadIdx.x;
  const int g   = bid * 1024 + tid;    // 0 .. BT-1
  o_cnt[g] = 0.0f;
  if (cur) cur[g] = 0;
  __shared__ unsigned h[8][4096];      // 128 KiB, 8-way privatization
  for (int i = tid; i < 8 * 4096; i += 1024) ((unsigned*)h)[i] = 0u;
  __syncthreads();
  const int copy = tid >> 7;           // 2 waves share a copy
  const float4* src = (const float4*)(scoresT + ((size_t)bid << 14));
#pragma unroll
  for (int it = 0; it < 4; ++it) {
    float4 v = src[it * 1024 + tid];
    atomicAdd(&h[copy][fkey(v.x) >> 20], 1u);
    atomicAdd(&h[copy][fkey(v.y) >> 20], 1u);
    atomicAdd(&h[copy][fkey(v.z) >> 20], 1u);
    atomicAdd(&h[copy][fkey(v.w) >> 20], 1u);
  }
  __syncthreads();
  unsigned* dst = parts + ((size_t)bid << 12);
  for (int j = tid; j < 4096; j += 1024) {
    unsigned s = 0;
#pragma unroll
    for (int c = 0; c < 8; ++c) s += h[c][j];
    dst[j] = s;
  }
}

// ---------------------------------------------------------------------------
// K2b: per-expert descending scan over summed parts -> 12-bit bucket of the
// rank-K key. Fused: zeros ccnt[e].
// ---------------------------------------------------------------------------
__global__ __launch_bounds__(256)
void k2b_scan(const unsigned* __restrict__ parts, unsigned* __restrict__ thr12,
              int* __restrict__ ccnt) {
  const int e = blockIdx.x;
  const unsigned* p = parts + ((size_t)e << 14);  // 4 parts x 4096
  __shared__ unsigned chs[256];
  const int tid = threadIdx.x;
  if (tid == 0) ccnt[e] = 0;
  const int lo = 4095 - tid * 16 - 15;  // chunk tid covers [lo, lo+15] desc
  unsigned s = 0;
  for (int j = 0; j < 16; ++j) {
    int b = lo + j;
    s += p[b] + p[4096 + b] + p[8192 + b] + p[12288 + b];
  }
  chs[tid] = s;
  __syncthreads();
  if (tid == 0) {
    unsigned cum = 0; int c = 0;
    for (; c < 255; ++c) {
      if (cum + chs[c] >= (unsigned)K) break;
      cum += chs[c];
    }
    int vb = 4095 - c * 16;
    unsigned b = 0;
    for (int j = 0; j < 16; ++j) {
      int bb = vb - j;
      cum += p[bb] + p[4096 + bb] + p[8192 + bb] + p[12288 + bb];
      if (cum >= (unsigned)K) { b = (unsigned)bb; break; }
    }
    thr12[e] = b;
  }
}

// ---------------------------------------------------------------------------
// K2c: parallel collect, 4 blocks/expert. LDS-local cursor; ONE global
// atomic per block reserves a segment of cand[e]; coalesced flush.
// NT loads: k2c is the LAST reader of scoresT.
// ---------------------------------------------------------------------------
__global__ __launch_bounds__(1024)
void k2c_collect(const float* __restrict__ scoresT,
                 const unsigned* __restrict__ thr12,
                 unsigned long long* __restrict__ cand,
                 int* __restrict__ ccnt) {
  const int bid = blockIdx.x;  // e*4 + q
  const int e = bid >> 2;
  const unsigned bthr = thr12[e] << 20;
  const float* row = scoresT + ((size_t)bid << 14);
  const unsigned ibase = (unsigned)(bid & 3) << 14;
  __shared__ int sh_n, sh_base;
  __shared__ unsigned long long lkeys[4096];
  const int tid = threadIdx.x;
  if (tid == 0) sh_n = 0;
  __syncthreads();
  for (int i = tid; i < 16384; i += 1024) {
    float sv = __builtin_nontemporal_load(&row[i]);
    unsigned u = fkey(sv);
    if (u >= bthr) {
      int pos = atomicAdd(&sh_n, 1);   // LDS atomic
      if (pos < 4096)
        lkeys[pos] =
            ((unsigned long long)u << 32) | (unsigned)(~(ibase + i));
    }
  }
  __syncthreads();
  int n = sh_n; if (n > 4096) n = 4096;
  if (tid == 0) sh_base = atomicAdd(&ccnt[e], n);  // one global atomic/block
  __syncthreads();
  const int base = sh_base;
  for (int i = tid; i < n; i += 1024)
    if (base + i < 4096) cand[((size_t)e << 12) + base + i] = lkeys[i];
}

// ---------------------------------------------------------------------------
// K2d: per-expert bitonic sort of candidates (score desc, idx asc) + output
// tail. Comparator network is order-canonical -> bit-identical results.
// NT loads for cand (read-once).
// ---------------------------------------------------------------------------
__global__ __launch_bounds__(1024)
void k2d_sort(const unsigned long long* __restrict__ cand,
              const int* __restrict__ ccnt,
              float* __restrict__ o_idx, float* __restrict__ o_scr,
              float* __restrict__ o_cnt,
              int* __restrict__ cur, int* __restrict__ slots) {
  const int e = blockIdx.x;
  __shared__ unsigned long long keys[4096];
  const int tid = threadIdx.x;
  int n = ccnt[e]; if (n > 4096) n = 4096;
  for (int i = tid; i < 4096; i += 1024)
    keys[i] = (i < n)
        ? __builtin_nontemporal_load(&cand[((size_t)e << 12) + i])
        : 0ull;
  __syncthreads();
  for (int kk = 2; kk <= 4096; kk <<= 1) {
    for (int j = kk >> 1; j > 0; j >>= 1) {
      for (int i = tid; i < 4096; i += 1024) {
        int ij = i ^ j;
        if (ij > i) {
          bool up = ((i & kk) == 0);
          unsigned long long a = keys[i], b = keys[ij];
          if ((a < b) == up) { keys[i] = b; keys[ij] = a; }
        }
      }
      __syncthreads();
    }
  }
  for (int r = tid; r < K; r += 1024) {
    unsigned long long kv = keys[r];
    unsigned u = (unsigned)(kv >> 32);
    unsigned idx = ~((unsigned)kv);
    float s = __uint_as_float((u & 0x80000000u) ? (u ^ 0x80000000u) : ~u);
    o_idx[(size_t)e * K + r] = (float)idx;
    o_scr[(size_t)e * K + r] = s;
    atomicAdd(&o_cnt[idx], 1.0f);
    if (slots) {
      int pos = atomicAdd(&cur[idx], 1);
      if (pos < SLOT_PAD) slots[(size_t)idx * SLOT_PAD + pos] = e * K + r;
    }
  }
}

// ---------------------------------------------------------------------------
// K3b: Bmat[e][n=2f+co][k=2d+ci] = bf16( ew[e][d][f][ci^co] * sign ).
// ---------------------------------------------------------------------------
__global__ __launch_bounds__(256)
void k3b_bmat(const float* __restrict__ ew, unsigned short* __restrict__ bm) {
  int id = blockIdx.x * 256 + threadIdx.x;
  int sub = id & 63;
  int ng  = id >> 6;
  int e   = ng >> 9;
  int n   = ng & 511;
  int f   = n >> 1, co = n & 1;
  int d0  = sub * 4;
  const float* wb = ew + (((size_t)e * 256) * 256 + f) * 2;
  union { unsigned short h[8]; bf16x8 v; } pk;
#pragma unroll
  for (int dd = 0; dd < 4; ++dd) {
    float2 wv = *(const float2*)(wb + (size_t)(d0 + dd) * 512);
    float b0 = co ? wv.y : wv.x;
    float b1 = co ? wv.x : -wv.y;
    pk.h[dd * 2]     = f2bf(b0);
    pk.h[dd * 2 + 1] = f2bf(b1);
  }
  ((bf16x8*)bm)[id] = pk.v;
}

// ---------------------------------------------------------------------------
// K4c (tier-1, v8): MFMA bf16 GEMM, dense fp16 output (NO atomics).
// 128x128 tile, BK=64, 2-phase double-buffered LDS, setprio(1) around MFMA
// cluster (T5, +13% measured), NT yD stores (write-once stream).
// ---------------------------------------------------------------------------
__global__ __launch_bounds__(256)
void k4c_mfma(const unsigned short* __restrict__ xb,
              const unsigned short* __restrict__ bm,
              const float* __restrict__ o_idx, const float* __restrict__ o_scr,
              unsigned short* __restrict__ yD) {
  const int bid = blockIdx.x;
  const int xcd = bid & 7;
  const int s   = bid >> 3;
  const int fn  = s & 3;
  const int km  = (s >> 2) & 15;
  const int e   = xcd + ((s >> 6) << 3);

  // sh: A dbuf = sh + cb*8192 (each 128 rows x 64 shorts);
  //     B dbuf = sh + 16384 + cb*8192. Pk overlay @0 (17408 shorts).
  __shared__ __align__(16) unsigned short sh[32768];
  __shared__ int   tIdx[128];
  __shared__ float wRow[128];
  const int tid = threadIdx.x;
  if (tid < 128) {
    size_t gi = (size_t)e * K + km * 128 + tid;
    tIdx[tid] = (int)o_idx[gi];
    wRow[tid] = o_scr[gi];
  }
  __syncthreads();

  const int lane = tid & 63;
  const int w    = tid >> 6;
  const int wr   = (w & 1) * 64;
  const int wc   = (w >> 1) * 64;
  const int l15  = lane & 15, l4 = lane >> 4;
  const int ls   = lane & 7, lr = lane >> 3;
  const int gch  = ls ^ lr;  // pre-swizzled source chunk (row&7 == lr)

  // per-lane global source bases and LDS dest offsets (shorts) per row-octet
  const char* aSrc[4];
  const char* bSrc[4];
  int dstOff[4];
#pragma unroll
  for (int i = 0; i < 4; ++i) {
    int r = w * 32 + i * 8 + lr;
    aSrc[i] = (const char*)xb + (size_t)tIdx[r] * 1024 + gch * 16;
    bSrc[i] = (const char*)bm + ((size_t)e * 512 + fn * 128 + r) * 1024 +
              gch * 16;
    dstOff[i] = (w * 32 + i * 8) * 64 + lane * 8;
  }

  f32x4 acc[4][4];
#pragma unroll
  for (int m = 0; m < 4; ++m)
#pragma unroll
    for (int n = 0; n < 4; ++n) acc[m][n] = (f32x4){0.f, 0.f, 0.f, 0.f};

  // prologue: K-step 0 into buffer 0
#pragma unroll
  for (int i = 0; i < 4; ++i) {
    gl16(aSrc[i], sh + dstOff[i]);
    gl16(bSrc[i], sh + 16384 + dstOff[i]);
  }

#pragma unroll
  for (int t = 0; t < 8; ++t) {
    const int cb = t & 1;
    __syncthreads();  // drains vmcnt -> buffer cb ready
    if (t < 7) {      // stage next tile into cb^1 while computing cb
      const int nxt = (cb ^ 1) * 8192;
#pragma unroll
      for (int i = 0; i < 4; ++i) {
        gl16(aSrc[i] + (t + 1) * 128, sh + nxt + dstOff[i]);
        gl16(bSrc[i] + (t + 1) * 128, sh + 16384 + nxt + dstOff[i]);
      }
    }
    const unsigned short* Ab = sh + cb * 8192;
    const unsigned short* Bb = sh + 16384 + cb * 8192;
#pragma unroll
    for (int kk2 = 0; kk2 < 2; ++kk2) {
      bf16x8 af[4], bfr[4];
#pragma unroll
      for (int m = 0; m < 4; ++m) {
        int r = wr + m * 16 + l15;
        int sw = (kk2 * 4 + l4) ^ (r & 7);
        af[m] = *(const bf16x8*)(&Ab[r * 64 + sw * 8]);
      }
#pragma unroll
      for (int n = 0; n < 4; ++n) {
        int cl = wc + n * 16 + l15;
        int sw = (kk2 * 4 + l4) ^ (cl & 7);
        bfr[n] = *(const bf16x8*)(&Bb[cl * 64 + sw * 8]);
      }
      __builtin_amdgcn_s_setprio(1);
#pragma unroll
      for (int m = 0; m < 4; ++m)
#pragma unroll
        for (int n = 0; n < 4; ++n)
          acc[m][n] = __builtin_amdgcn_mfma_f32_16x16x32_bf16(
              af[m], bfr[n], acc[m][n], 0, 0, 0);
      __builtin_amdgcn_s_setprio(0);
    }
  }

  // epilogue: weight, fp16-pack via padded-LDS repack (stride 136), NT store
  __syncthreads();
  unsigned short* Pk = sh;  // 128 x 136 = 17408 shorts (fits in 32768)
#pragma unroll
  for (int m = 0; m < 4; ++m) {
#pragma unroll
    for (int q = 0; q < 4; ++q) {
      int row = wr + m * 16 + l4 * 4 + q;
      float wv = wRow[row];
#pragma unroll
      for (int n = 0; n < 4; ++n) {
        int col = wc + n * 16 + l15;
        Pk[row * 136 + col] =
            __half_as_ushort(__float2half(acc[m][n][q] * wv));
      }
    }
  }
  __syncthreads();
  const size_t rowBase = (size_t)e * K + km * 128;
#pragma unroll
  for (int i = 0; i < 8; ++i) {
    int c2 = tid + 256 * i;
    int row = c2 >> 4, ch = c2 & 15;
    u32x4 v = *(const u32x4*)(&Pk[row * 136 + ch * 8]);
    __builtin_nontemporal_store(
        v, (u32x4*)(yD + (rowBase + row) * 512 + fn * 128 + ch * 8));
  }
}

// ---------------------------------------------------------------------------
// K5g (tier-1): per-token gather-finalize (one wave per token).
// NT loads for yD (read-once) and NT stores for res (write-once).
// ---------------------------------------------------------------------------
__global__ __launch_bounds__(256)
void k5g(const unsigned short* __restrict__ yD, const int* __restrict__ cur,
         const int* __restrict__ slots, const float* __restrict__ bias,
         float* __restrict__ res) {
  const int t    = blockIdx.x * 4 + (threadIdx.x >> 6);
  const int lane = threadIdx.x & 63;
  const int nc   = cur[t];
  const int ncc  = nc < SLOT_PAD ? nc : SLOT_PAD;
  float acc[8] = {};
  const int* sl = slots + (size_t)t * SLOT_PAD;
  for (int c = 0; c < ncc; ++c) {
    int slot = sl[c];
    union { u32x4 v; unsigned short h[8]; } U;
    U.v = __builtin_nontemporal_load(
        (const u32x4*)(yD + (size_t)slot * 512 + lane * 8));
#pragma unroll
    for (int j = 0; j < 8; ++j)
      acc[j] += __half2float(__ushort_as_half(U.h[j]));
  }
  const float inv = 1.0f / fmaxf((float)nc, 1.0f);
  float4 b4 = *(const float4*)(bias + lane * 4);
  const float* bp = (const float*)&b4;
  const float is2 = 0.70710678118654752f;
  float r8[8];
#pragma unroll
  for (int j = 0; j < 8; ++j) {
    float h = acc[j] * inv + bp[j >> 1];
    r8[j] = 0.5f * h * (1.0f + erff(h * is2));
  }
  float* dst = res + (size_t)t * J + lane * 8;
  f32x4 lo = (f32x4){r8[0], r8[1], r8[2], r8[3]};
  f32x4 hi = (f32x4){r8[4], r8[5], r8[6], r8[7]};
  __builtin_nontemporal_store(lo, (f32x4*)dst);
  __builtin_nontemporal_store(hi, (f32x4*)(dst + 4));
}

// ---------------------------------------------------------------------------
// K4b (tier-2 fallback): atomic-scatter MFMA GEMM (round-7 verified).
// ---------------------------------------------------------------------------
__global__ __launch_bounds__(256)
void k4b_mfma(const unsigned short* __restrict__ xb,
              const unsigned short* __restrict__ bm,
              const float* __restrict__ o_idx, const float* __restrict__ o_scr,
              float* __restrict__ out) {
  const int e  = blockIdx.z;
  const int km = blockIdx.y;
  const int fn = blockIdx.x;
  __shared__ __align__(16) unsigned short As[128 * 64];
  __shared__ __align__(16) unsigned short Bs[128 * 64];
  __shared__ int   tIdx[128];
  __shared__ float wRow[128];
  const int tid = threadIdx.x;
  if (tid < 128) {
    size_t gi = (size_t)e * K + km * 128 + tid;
    tIdx[tid] = (int)o_idx[gi];
    wRow[tid] = o_scr[gi];
  }
  __syncthreads();

  const int lane = tid & 63;
  const int w    = tid >> 6;
  const int wr   = (w & 1) * 64;
  const int wc   = (w >> 1) * 64;
  const int l15  = lane & 15, l4 = lane >> 4;
  const int ls   = lane & 7, lr = lane >> 3;
  const int gch  = ls ^ lr;

  const char* aSrc[4];
  const char* bSrc[4];
  unsigned short* aDst[4];
  unsigned short* bDst[4];
#pragma unroll
  for (int i = 0; i < 4; ++i) {
    int r = w * 32 + i * 8 + lr;
    aSrc[i] = (const char*)xb + (size_t)tIdx[r] * 1024 + gch * 16;
    bSrc[i] = (const char*)bm + ((size_t)e * 512 + fn * 128 + r) * 1024 +
              gch * 16;
    aDst[i] = As + (w * 32 + i * 8) * 64 + lane * 8;
    bDst[i] = Bs + (w * 32 + i * 8) * 64 + lane * 8;
  }

  f32x4 acc[4][4];
#pragma unroll
  for (int m = 0; m < 4; ++m)
#pragma unroll
    for (int n = 0; n < 4; ++n) acc[m][n] = (f32x4){0.f, 0.f, 0.f, 0.f};

  for (int kk = 0; kk < J; kk += 64) {
#pragma unroll
    for (int i = 0; i < 4; ++i) {
      gl16(aSrc[i] + kk * 2, aDst[i]);
      gl16(bSrc[i] + kk * 2, bDst[i]);
    }
    __syncthreads();
#pragma unroll
    for (int kk2 = 0; kk2 < 2; ++kk2) {
      bf16x8 af[4], bfr[4];
#pragma unroll
      for (int m = 0; m < 4; ++m) {
        int r = wr + m * 16 + l15;
        int s = (kk2 * 4 + l4) ^ (r & 7);
        af[m] = *(const bf16x8*)(&As[r * 64 + s * 8]);
      }
#pragma unroll
      for (int n = 0; n < 4; ++n) {
        int cl = wc + n * 16 + l15;
        int s = (kk2 * 4 + l4) ^ (cl & 7);
        bfr[n] = *(const bf16x8*)(&Bs[cl * 64 + s * 8]);
      }
#pragma unroll
      for (int m = 0; m < 4; ++m)
#pragma unroll
        for (int n = 0; n < 4; ++n)
          acc[m][n] = __builtin_amdgcn_mfma_f32_16x16x32_bf16(
              af[m], bfr[n], acc[m][n], 0, 0, 0);
    }
    __syncthreads();
  }

#pragma unroll
  for (int m = 0; m < 4; ++m) {
#pragma unroll
    for (int q = 0; q < 4; ++q) {
      int rl = wr + m * 16 + l4 * 4 + q;
      int t = tIdx[rl];
      float wv = wRow[rl];
      float* dst = out + (size_t)t * J + fn * 128 + wc + l15;
#pragma unroll
      for (int n = 0; n < 4; ++n)
        atomicAdd(dst + n * 16, acc[m][n][q] * wv);
    }
  }
}

// ---------------------------------------------------------------------------
// K5 (tier-2 fallback): res = gelu(out/max(cnt,1)+bias), in place.
// ---------------------------------------------------------------------------
__global__ __launch_bounds__(256)
void k5_final(float* __restrict__ res, const float* __restrict__ cnt,
              const float* __restrict__ bias) {
  const int total4 = BT * J / 4;
  for (int i = blockIdx.x * blockDim.x + threadIdx.x; i < total4;
       i += gridDim.x * blockDim.x) {
    float4 v = reinterpret_cast<float4*>(res)[i];
    int base = i << 2;
    int t = base >> 9;
    int col = base & 511;
    float inv = 1.0f / fmaxf(cnt[t], 1.0f);
    int f0 = col >> 1;
    float b0 = bias[f0], b1 = bias[f0 + 1];
    float h0 = v.x * inv + b0;
    float h1 = v.y * inv + b0;
    float h2 = v.z * inv + b1;
    float h3 = v.w * inv + b1;
    const float is2 = 0.70710678118654752f;
    v.x = 0.5f * h0 * (1.0f + erff(h0 * is2));
    v.y = 0.5f * h1 * (1.0f + erff(h1 * is2));
    v.z = 0.5f * h2 * (1.0f + erff(h2 * is2));
    v.w = 0.5f * h3 * (1.0f + erff(h3 * is2));
    reinterpret_cast<float4*>(res)[i] = v;
  }
}

// ---------------------------------------------------------------------------
extern "C" void kernel_launch(void* const* d_in, const int* in_sizes, int n_in,
                              void* d_out, int out_size, void* d_ws,
                              size_t ws_size, hipStream_t stream) {
  const float* x    = (const float*)d_in[0];
  const float* gw   = (const float*)d_in[1];
  const float* ew   = (const float*)d_in[2];
  const float* bias = (const float*)d_in[3];

  float* out_f = (float*)d_out;
  float* res   = out_f;
  float* o_idx = out_f + OFF_IDX;
  float* o_scr = out_f + OFF_SCR;
  float* o_cnt = out_f + OFF_CNT;

  // Borrowed regions inside res (all rewritten later by k5g/k5):
  //   scoresT @ 0 (16.8 MB) | parts @ 32 MB | thr12 @ 36 MB |
  //   cand @ 48 MB (2 MB) | ccnt @ 52 MB
  float*              scoresT = res;
  unsigned*           parts   = (unsigned*)((char*)res + (size_t)32 * 1024 * 1024);
  unsigned*           thr12   = (unsigned*)((char*)res + (size_t)36 * 1024 * 1024);
  unsigned long long* cand    = (unsigned long long*)((char*)res + (size_t)48 * 1024 * 1024);
  int*                ccnt    = (int*)((char*)res + (size_t)52 * 1024 * 1024);

  unsigned short* xb  = (unsigned short*)((char*)d_ws + WS_XB);
  unsigned short* bm  = (unsigned short*)((char*)d_ws + WS_BM);
  unsigned short* yD  = (unsigned short*)((char*)d_ws + WS_YD);
  int*            cur = (int*)((char*)d_ws + WS_CUR);
  int*            slt = (int*)((char*)d_ws + WS_SLOT);

  const bool tier1 = (ws_size >= WS_NEED1);
  const bool tier2 = (ws_size >= WS_NEED2);

  if (tier2) k3b_bmat<<<8192, 256, 0, stream>>>(ew, bm);

  k1_scores<<<BT / 64, 256, 0, stream>>>(x, gw, scoresT,
                                         tier2 ? xb : nullptr);
  k2a_hist<<<E * 4, 1024, 0, stream>>>(scoresT, parts, o_cnt,
                                       tier1 ? cur : nullptr);
  k2b_scan<<<E, 256, 0, stream>>>(parts, thr12, ccnt);
  k2c_collect<<<E * 4, 1024, 0, stream>>>(scoresT, thr12, cand, ccnt);
  k2d_sort<<<E, 1024, 0, stream>>>(cand, ccnt, o_idx, o_scr, o_cnt,
                                   tier1 ? cur : nullptr,
                                   tier1 ? slt : nullptr);
  if (tier1) {
    k4c_mfma<<<4096, 256, 0, stream>>>(xb, bm, o_idx, o_scr, yD);
    k5g<<<BT / 4, 256, 0, stream>>>(yD, cur, slt, bias, res);
  } else if (tier2) {
    hipMemsetAsync(res, 0, (size_t)BT * J * sizeof(float), stream);
    k4b_mfma<<<dim3(4, 16, E), 256, 0, stream>>>(xb, bm, o_idx, o_scr, res);
    k5_final<<<8192, 256, 0, stream>>>(res, o_cnt, bias);
  }
}

// Round 22
// 349.297 us; speedup vs baseline: 1.0928x; 1.0734x over previous
//
#include <hip/hip_runtime.h>
#include <hip/hip_fp16.h>
#include <math.h>

constexpr int BT = 65536;
constexpr int D  = 256;
constexpr int E  = 64;
constexpr int K  = 2048;
constexpr int J  = 512; // 2*D

// d_out layout (floats): res | topk_idx | topk_scores | counts
constexpr size_t OFF_IDX = (size_t)BT * D * 2;       // 33,554,432
constexpr size_t OFF_SCR = OFF_IDX + (size_t)E * K;  // +131,072
constexpr size_t OFF_CNT = OFF_SCR + (size_t)E * K;  // +131,072

// d_ws layout (bytes):
//   xb   bf16[BT][512]        @ 0          (64 MiB)
//   bm   bf16[E][512][512]    @ 64 MiB     (32 MiB)
//   yD   fp16[E*K][512]       @ 96 MiB     (128 MiB)   [tier-1 only]
//   cur  int[BT]              @ 224 MiB    (256 KiB)   [tier-1 only]
//   slot int[BT][32]          @ 224.25 MiB (8 MiB)     [tier-1 only]
constexpr size_t WS_XB    = 0;
constexpr size_t WS_BM    = 67108864;
constexpr size_t WS_YD    = 100663296;
constexpr size_t WS_CUR   = 234881024;
constexpr size_t WS_SLOT  = 235143168;
constexpr size_t WS_NEED1 = 243531776;              // tier-1: full path
constexpr size_t WS_NEED2 = 100663296;              // tier-2 path
constexpr int    SLOT_PAD = 32;

typedef __attribute__((ext_vector_type(8))) short bf16x8;
typedef __attribute__((ext_vector_type(4))) float f32x4;
typedef __attribute__((ext_vector_type(4))) unsigned int u32x4;

__device__ __forceinline__ unsigned short f2bf(float f) {
  unsigned u = __float_as_uint(f);
  u = (u + 0x7FFFu + ((u >> 16) & 1u)) >> 16;  // RTNE
  return (unsigned short)u;
}

__device__ __forceinline__ void gl16(const void* g, void* l) {
  __builtin_amdgcn_global_load_lds(
      (const __attribute__((address_space(1))) unsigned int*)g,
      (__attribute__((address_space(3))) unsigned int*)l, 16, 0, 0);
}

__device__ __forceinline__ unsigned fkey(float s) {
  unsigned u = __float_as_uint(s);
  return (u & 0x80000000u) ? ~u : (u | 0x80000000u);
}

// ---------------------------------------------------------------------------
// K1 (v4 = v3 + fused k3b slice): scoresT[e][t] = fp32 dot as ONE sequential
// FMA chain j=0..511 (bit-matches np's sgemm scheme — chain order UNCHANGED).
// 64-token blocks (grid 1024, 4 blocks/CU), thread tile 4 tok x 4 exp.
// b128 LDS reads; NT x loads; fused bf16 emit (xbp != null).
// Fused epilogue: each block also emits 2048 bf16x8 elements of Bmat
// (independent of k1's work; consumer k4c runs 4 launches later) — absorbs
// the former serial k3b dispatch into k1's latency slack.
// ---------------------------------------------------------------------------
__global__ __launch_bounds__(256)
void k1_scores(const float* __restrict__ x, const float* __restrict__ gw,
               float* __restrict__ scoresT, unsigned short* __restrict__ xbp,
               const float* __restrict__ ew, unsigned short* __restrict__ bmp) {
  __shared__ float xs[64][68];    // 17.4 KB
  __shared__ float gsT[64][68];   // 17.4 KB
  const int t0 = blockIdx.x * 64;
  const int tid = threadIdx.x;
  const int tx = tid & 15;   // token sub-index (4 tokens: a*16+tx)
  const int ty = tid >> 4;   // expert group (4 experts: ty*4+b)
  float acc[4][4] = {};

  for (int kk = 0; kk < 8; ++kk) {
    // ---- stage x (float4 coalesced, NT) + fused bf16 emit
#pragma unroll
    for (int i = 0; i < 4; ++i) {
      int idx = tid + 256 * i;
      int r = idx >> 4, c4 = (idx & 15) * 4;
      f32x4 v = __builtin_nontemporal_load(
          (const f32x4*)(&x[(size_t)(t0 + r) * J + kk * 64 + c4]));
      *(f32x4*)(&xs[r][c4]) = v;
      if (xbp) {
        uint2 u;
        u.x = (unsigned)f2bf(v.x) | ((unsigned)f2bf(v.y) << 16);
        u.y = (unsigned)f2bf(v.z) | ((unsigned)f2bf(v.w) << 16);
        *(uint2*)(&xbp[(size_t)(t0 + r) * J + kk * 64 + c4]) = u;
      }
    }
    // ---- stage gw transposed: gsT[e][j]
#pragma unroll
    for (int i = 0; i < 4; ++i) {
      int idx = tid + 256 * i;
      int r = idx >> 4, c4 = (idx & 15) * 4;   // r = j-local, c4 = expert
      float4 v = *(const float4*)(&gw[(size_t)(kk * 64 + r) * E + c4]);
      gsT[c4][r]     = v.x;
      gsT[c4 + 1][r] = v.y;
      gsT[c4 + 2][r] = v.z;
      gsT[c4 + 3][r] = v.w;
    }
    __syncthreads();
    // ---- compute: j in groups of 4, b128 reads, chain order preserved
#pragma unroll 4
    for (int j = 0; j < 64; j += 4) {
      float4 xv[4], gv[4];
#pragma unroll
      for (int a = 0; a < 4; ++a)
        xv[a] = *(const float4*)(&xs[a * 16 + tx][j]);
#pragma unroll
      for (int b = 0; b < 4; ++b)
        gv[b] = *(const float4*)(&gsT[ty * 4 + b][j]);
#define K1_FMA(COMP)                                                        \
  _Pragma("unroll") for (int a = 0; a < 4; ++a)                             \
    _Pragma("unroll") for (int b = 0; b < 4; ++b)                           \
      acc[a][b] = fmaf(xv[a].COMP, gv[b].COMP, acc[a][b]);
      K1_FMA(x) K1_FMA(y) K1_FMA(z) K1_FMA(w)
#undef K1_FMA
    }
    __syncthreads();
  }

#pragma unroll
  for (int b = 0; b < 4; ++b) {
    int e = ty * 4 + b;
#pragma unroll
    for (int a = 0; a < 4; ++a)
      scoresT[(size_t)e * BT + t0 + a * 16 + tx] = acc[a][b];
  }

  // ---- fused k3b slice: Bmat[e][n=2f+co][k=2d+ci] = bf16(ew * sign)
  if (bmp) {
#pragma unroll
    for (int i = 0; i < 8; ++i) {
      int id  = blockIdx.x * 2048 + i * 256 + tid;  // 0 .. 2M-1
      int sub = id & 63;
      int ng  = id >> 6;
      int e   = ng >> 9;
      int n   = ng & 511;
      int f   = n >> 1, co = n & 1;
      int d0  = sub * 4;
      const float* wb = ew + (((size_t)e * 256) * 256 + f) * 2;
      union { unsigned short h[8]; bf16x8 v; } pk;
#pragma unroll
      for (int dd = 0; dd < 4; ++dd) {
        float2 wv = *(const float2*)(wb + (size_t)(d0 + dd) * 512);
        float b0 = co ? wv.y : wv.x;
        float b1 = co ? wv.x : -wv.y;
        pk.h[dd * 2]     = f2bf(b0);
        pk.h[dd * 2 + 1] = f2bf(b1);
      }
      ((bf16x8*)bmp)[id] = pk.v;
    }
  }
}

// ---------------------------------------------------------------------------
// K2a: 12-bit-key histogram, 4 blocks/expert, 8-way privatized LDS, then a
// NON-atomic partial write to parts[bid][4096].
// Fused: zeros o_cnt and cur (256 blocks x 1024 threads == BT exactly).
// ---------------------------------------------------------------------------
__global__ __launch_bounds__(1024)
void k2a_hist(const float* __restrict__ scoresT, unsigned* __restrict__ parts,
              float* __restrict__ o_cnt, int* __restrict__ cur) {
  const int bid = blockIdx.x;          // e*4 + q
  const int tid = threadIdx.x;
  const int g   = bid * 1024 + tid;    // 0 .. BT-1
  o_cnt[g] = 0.0f;
  if (cur) cur[g] = 0;
  __shared__ unsigned h[8][4096];      // 128 KiB, 8-way privatization
  for (int i = tid; i < 8 * 4096; i += 1024) ((unsigned*)h)[i] = 0u;
  __syncthreads();
  const int copy = tid >> 7;           // 2 waves share a copy
  const float4* src = (const float4*)(scoresT + ((size_t)bid << 14));
#pragma unroll
  for (int it = 0; it < 4; ++it) {
    float4 v = src[it * 1024 + tid];
    atomicAdd(&h[copy][fkey(v.x) >> 20], 1u);
    atomicAdd(&h[copy][fkey(v.y) >> 20], 1u);
    atomicAdd(&h[copy][fkey(v.z) >> 20], 1u);
    atomicAdd(&h[copy][fkey(v.w) >> 20], 1u);
  }
  __syncthreads();
  unsigned* dst = parts + ((size_t)bid << 12);
  for (int j = tid; j < 4096; j += 1024) {
    unsigned s = 0;
#pragma unroll
    for (int c = 0; c < 8; ++c) s += h[c][j];
    dst[j] = s;
  }
}

// ---------------------------------------------------------------------------
// K2b: per-expert descending scan over summed parts -> 12-bit bucket of the
// rank-K key. Fused: zeros ccnt[e].
// ---------------------------------------------------------------------------
__global__ __launch_bounds__(256)
void k2b_scan(const unsigned* __restrict__ parts, unsigned* __restrict__ thr12,
              int* __restrict__ ccnt) {
  const int e = blockIdx.x;
  const unsigned* p = parts + ((size_t)e << 14);  // 4 parts x 4096
  __shared__ unsigned chs[256];
  const int tid = threadIdx.x;
  if (tid == 0) ccnt[e] = 0;
  const int lo = 4095 - tid * 16 - 15;  // chunk tid covers [lo, lo+15] desc
  unsigned s = 0;
  for (int j = 0; j < 16; ++j) {
    int b = lo + j;
    s += p[b] + p[4096 + b] + p[8192 + b] + p[12288 + b];
  }
  chs[tid] = s;
  __syncthreads();
  if (tid == 0) {
    unsigned cum = 0; int c = 0;
    for (; c < 255; ++c) {
      if (cum + chs[c] >= (unsigned)K) break;
      cum += chs[c];
    }
    int vb = 4095 - c * 16;
    unsigned b = 0;
    for (int j = 0; j < 16; ++j) {
      int bb = vb - j;
      cum += p[bb] + p[4096 + bb] + p[8192 + bb] + p[12288 + bb];
      if (cum >= (unsigned)K) { b = (unsigned)bb; break; }
    }
    thr12[e] = b;
  }
}

// ---------------------------------------------------------------------------
// K2c: parallel collect, 4 blocks/expert. LDS-local cursor; ONE global
// atomic per block reserves a segment of cand[e]; coalesced flush.
// NT loads: k2c is the LAST reader of scoresT.
// ---------------------------------------------------------------------------
__global__ __launch_bounds__(1024)
void k2c_collect(const float* __restrict__ scoresT,
                 const unsigned* __restrict__ thr12,
                 unsigned long long* __restrict__ cand,
                 int* __restrict__ ccnt) {
  const int bid = blockIdx.x;  // e*4 + q
  const int e = bid >> 2;
  const unsigned bthr = thr12[e] << 20;
  const float* row = scoresT + ((size_t)bid << 14);
  const unsigned ibase = (unsigned)(bid & 3) << 14;
  __shared__ int sh_n, sh_base;
  __shared__ unsigned long long lkeys[4096];
  const int tid = threadIdx.x;
  if (tid == 0) sh_n = 0;
  __syncthreads();
  for (int i = tid; i < 16384; i += 1024) {
    float sv = __builtin_nontemporal_load(&row[i]);
    unsigned u = fkey(sv);
    if (u >= bthr) {
      int pos = atomicAdd(&sh_n, 1);   // LDS atomic
      if (pos < 4096)
        lkeys[pos] =
            ((unsigned long long)u << 32) | (unsigned)(~(ibase + i));
    }
  }
  __syncthreads();
  int n = sh_n; if (n > 4096) n = 4096;
  if (tid == 0) sh_base = atomicAdd(&ccnt[e], n);  // one global atomic/block
  __syncthreads();
  const int base = sh_base;
  for (int i = tid; i < n; i += 1024)
    if (base + i < 4096) cand[((size_t)e << 12) + base + i] = lkeys[i];
}

// ---------------------------------------------------------------------------
// K2d: per-expert bitonic sort of candidates (score desc, idx asc) + output
// tail. Comparator network is order-canonical -> bit-identical results.
// NT loads for cand (read-once).
// ---------------------------------------------------------------------------
__global__ __launch_bounds__(1024)
void k2d_sort(const unsigned long long* __restrict__ cand,
              const int* __restrict__ ccnt,
              float* __restrict__ o_idx, float* __restrict__ o_scr,
              float* __restrict__ o_cnt,
              int* __restrict__ cur, int* __restrict__ slots) {
  const int e = blockIdx.x;
  __shared__ unsigned long long keys[4096];
  const int tid = threadIdx.x;
  int n = ccnt[e]; if (n > 4096) n = 4096;
  for (int i = tid; i < 4096; i += 1024)
    keys[i] = (i < n)
        ? __builtin_nontemporal_load(&cand[((size_t)e << 12) + i])
        : 0ull;
  __syncthreads();
  for (int kk = 2; kk <= 4096; kk <<= 1) {
    for (int j = kk >> 1; j > 0; j >>= 1) {
      for (int i = tid; i < 4096; i += 1024) {
        int ij = i ^ j;
        if (ij > i) {
          bool up = ((i & kk) == 0);
          unsigned long long a = keys[i], b = keys[ij];
          if ((a < b) == up) { keys[i] = b; keys[ij] = a; }
        }
      }
      __syncthreads();
    }
  }
  for (int r = tid; r < K; r += 1024) {
    unsigned long long kv = keys[r];
    unsigned u = (unsigned)(kv >> 32);
    unsigned idx = ~((unsigned)kv);
    float s = __uint_as_float((u & 0x80000000u) ? (u ^ 0x80000000u) : ~u);
    o_idx[(size_t)e * K + r] = (float)idx;
    o_scr[(size_t)e * K + r] = s;
    atomicAdd(&o_cnt[idx], 1.0f);
    if (slots) {
      int pos = atomicAdd(&cur[idx], 1);
      if (pos < SLOT_PAD) slots[(size_t)idx * SLOT_PAD + pos] = e * K + r;
    }
  }
}

// ---------------------------------------------------------------------------
// K3b (tier-2 fallback only): Bmat[e][n][k] = bf16( ew * sign ).
// ---------------------------------------------------------------------------
__global__ __launch_bounds__(256)
void k3b_bmat(const float* __restrict__ ew, unsigned short* __restrict__ bm) {
  int id = blockIdx.x * 256 + threadIdx.x;
  int sub = id & 63;
  int ng  = id >> 6;
  int e   = ng >> 9;
  int n   = ng & 511;
  int f   = n >> 1, co = n & 1;
  int d0  = sub * 4;
  const float* wb = ew + (((size_t)e * 256) * 256 + f) * 2;
  union { unsigned short h[8]; bf16x8 v; } pk;
#pragma unroll
  for (int dd = 0; dd < 4; ++dd) {
    float2 wv = *(const float2*)(wb + (size_t)(d0 + dd) * 512);
    float b0 = co ? wv.y : wv.x;
    float b1 = co ? wv.x : -wv.y;
    pk.h[dd * 2]     = f2bf(b0);
    pk.h[dd * 2 + 1] = f2bf(b1);
  }
  ((bf16x8*)bm)[id] = pk.v;
}

// ---------------------------------------------------------------------------
// K4c (tier-1, v8): MFMA bf16 GEMM, dense fp16 output (NO atomics).
// 128x128 tile, BK=64, 2-phase double-buffered LDS, setprio(1) around MFMA
// cluster (T5, +13% measured), NT yD stores (write-once stream).
// ---------------------------------------------------------------------------
__global__ __launch_bounds__(256)
void k4c_mfma(const unsigned short* __restrict__ xb,
              const unsigned short* __restrict__ bm,
              const float* __restrict__ o_idx, const float* __restrict__ o_scr,
              unsigned short* __restrict__ yD) {
  const int bid = blockIdx.x;
  const int xcd = bid & 7;
  const int s   = bid >> 3;
  const int fn  = s & 3;
  const int km  = (s >> 2) & 15;
  const int e   = xcd + ((s >> 6) << 3);

  // sh: A dbuf = sh + cb*8192 (each 128 rows x 64 shorts);
  //     B dbuf = sh + 16384 + cb*8192. Pk overlay @0 (17408 shorts).
  __shared__ __align__(16) unsigned short sh[32768];
  __shared__ int   tIdx[128];
  __shared__ float wRow[128];
  const int tid = threadIdx.x;
  if (tid < 128) {
    size_t gi = (size_t)e * K + km * 128 + tid;
    tIdx[tid] = (int)o_idx[gi];
    wRow[tid] = o_scr[gi];
  }
  __syncthreads();

  const int lane = tid & 63;
  const int w    = tid >> 6;
  const int wr   = (w & 1) * 64;
  const int wc   = (w >> 1) * 64;
  const int l15  = lane & 15, l4 = lane >> 4;
  const int ls   = lane & 7, lr = lane >> 3;
  const int gch  = ls ^ lr;  // pre-swizzled source chunk (row&7 == lr)

  // per-lane global source bases and LDS dest offsets (shorts) per row-octet
  const char* aSrc[4];
  const char* bSrc[4];
  int dstOff[4];
#pragma unroll
  for (int i = 0; i < 4; ++i) {
    int r = w * 32 + i * 8 + lr;
    aSrc[i] = (const char*)xb + (size_t)tIdx[r] * 1024 + gch * 16;
    bSrc[i] = (const char*)bm + ((size_t)e * 512 + fn * 128 + r) * 1024 +
              gch * 16;
    dstOff[i] = (w * 32 + i * 8) * 64 + lane * 8;
  }

  f32x4 acc[4][4];
#pragma unroll
  for (int m = 0; m < 4; ++m)
#pragma unroll
    for (int n = 0; n < 4; ++n) acc[m][n] = (f32x4){0.f, 0.f, 0.f, 0.f};

  // prologue: K-step 0 into buffer 0
#pragma unroll
  for (int i = 0; i < 4; ++i) {
    gl16(aSrc[i], sh + dstOff[i]);
    gl16(bSrc[i], sh + 16384 + dstOff[i]);
  }

#pragma unroll
  for (int t = 0; t < 8; ++t) {
    const int cb = t & 1;
    __syncthreads();  // drains vmcnt -> buffer cb ready
    if (t < 7) {      // stage next tile into cb^1 while computing cb
      const int nxt = (cb ^ 1) * 8192;
#pragma unroll
      for (int i = 0; i < 4; ++i) {
        gl16(aSrc[i] + (t + 1) * 128, sh + nxt + dstOff[i]);
        gl16(bSrc[i] + (t + 1) * 128, sh + 16384 + nxt + dstOff[i]);
      }
    }
    const unsigned short* Ab = sh + cb * 8192;
    const unsigned short* Bb = sh + 16384 + cb * 8192;
#pragma unroll
    for (int kk2 = 0; kk2 < 2; ++kk2) {
      bf16x8 af[4], bfr[4];
#pragma unroll
      for (int m = 0; m < 4; ++m) {
        int r = wr + m * 16 + l15;
        int sw = (kk2 * 4 + l4) ^ (r & 7);
        af[m] = *(const bf16x8*)(&Ab[r * 64 + sw * 8]);
      }
#pragma unroll
      for (int n = 0; n < 4; ++n) {
        int cl = wc + n * 16 + l15;
        int sw = (kk2 * 4 + l4) ^ (cl & 7);
        bfr[n] = *(const bf16x8*)(&Bb[cl * 64 + sw * 8]);
      }
      __builtin_amdgcn_s_setprio(1);
#pragma unroll
      for (int m = 0; m < 4; ++m)
#pragma unroll
        for (int n = 0; n < 4; ++n)
          acc[m][n] = __builtin_amdgcn_mfma_f32_16x16x32_bf16(
              af[m], bfr[n], acc[m][n], 0, 0, 0);
      __builtin_amdgcn_s_setprio(0);
    }
  }

  // epilogue: weight, fp16-pack via padded-LDS repack (stride 136), NT store
  __syncthreads();
  unsigned short* Pk = sh;  // 128 x 136 = 17408 shorts (fits in 32768)
#pragma unroll
  for (int m = 0; m < 4; ++m) {
#pragma unroll
    for (int q = 0; q < 4; ++q) {
      int row = wr + m * 16 + l4 * 4 + q;
      float wv = wRow[row];
#pragma unroll
      for (int n = 0; n < 4; ++n) {
        int col = wc + n * 16 + l15;
        Pk[row * 136 + col] =
            __half_as_ushort(__float2half(acc[m][n][q] * wv));
      }
    }
  }
  __syncthreads();
  const size_t rowBase = (size_t)e * K + km * 128;
#pragma unroll
  for (int i = 0; i < 8; ++i) {
    int c2 = tid + 256 * i;
    int row = c2 >> 4, ch = c2 & 15;
    u32x4 v = *(const u32x4*)(&Pk[row * 136 + ch * 8]);
    __builtin_nontemporal_store(
        v, (u32x4*)(yD + (rowBase + row) * 512 + fn * 128 + ch * 8));
  }
}

// ---------------------------------------------------------------------------
// K5g (tier-1): per-token gather-finalize (one wave per token).
// NT loads for yD (read-once) and NT stores for res (write-once).
// ---------------------------------------------------------------------------
__global__ __launch_bounds__(256)
void k5g(const unsigned short* __restrict__ yD, const int* __restrict__ cur,
         const int* __restrict__ slots, const float* __restrict__ bias,
         float* __restrict__ res) {
  const int t    = blockIdx.x * 4 + (threadIdx.x >> 6);
  const int lane = threadIdx.x & 63;
  const int nc   = cur[t];
  const int ncc  = nc < SLOT_PAD ? nc : SLOT_PAD;
  float acc[8] = {};
  const int* sl = slots + (size_t)t * SLOT_PAD;
  for (int c = 0; c < ncc; ++c) {
    int slot = sl[c];
    union { u32x4 v; unsigned short h[8]; } U;
    U.v = __builtin_nontemporal_load(
        (const u32x4*)(yD + (size_t)slot * 512 + lane * 8));
#pragma unroll
    for (int j = 0; j < 8; ++j)
      acc[j] += __half2float(__ushort_as_half(U.h[j]));
  }
  const float inv = 1.0f / fmaxf((float)nc, 1.0f);
  float4 b4 = *(const float4*)(bias + lane * 4);
  const float* bp = (const float*)&b4;
  const float is2 = 0.70710678118654752f;
  float r8[8];
#pragma unroll
  for (int j = 0; j < 8; ++j) {
    float h = acc[j] * inv + bp[j >> 1];
    r8[j] = 0.5f * h * (1.0f + erff(h * is2));
  }
  float* dst = res + (size_t)t * J + lane * 8;
  f32x4 lo = (f32x4){r8[0], r8[1], r8[2], r8[3]};
  f32x4 hi = (f32x4){r8[4], r8[5], r8[6], r8[7]};
  __builtin_nontemporal_store(lo, (f32x4*)dst);
  __builtin_nontemporal_store(hi, (f32x4*)(dst + 4));
}

// ---------------------------------------------------------------------------
// K4b (tier-2 fallback): atomic-scatter MFMA GEMM (round-7 verified).
// ---------------------------------------------------------------------------
__global__ __launch_bounds__(256)
void k4b_mfma(const unsigned short* __restrict__ xb,
              const unsigned short* __restrict__ bm,
              const float* __restrict__ o_idx, const float* __restrict__ o_scr,
              float* __restrict__ out) {
  const int e  = blockIdx.z;
  const int km = blockIdx.y;
  const int fn = blockIdx.x;
  __shared__ __align__(16) unsigned short As[128 * 64];
  __shared__ __align__(16) unsigned short Bs[128 * 64];
  __shared__ int   tIdx[128];
  __shared__ float wRow[128];
  const int tid = threadIdx.x;
  if (tid < 128) {
    size_t gi = (size_t)e * K + km * 128 + tid;
    tIdx[tid] = (int)o_idx[gi];
    wRow[tid] = o_scr[gi];
  }
  __syncthreads();

  const int lane = tid & 63;
  const int w    = tid >> 6;
  const int wr   = (w & 1) * 64;
  const int wc   = (w >> 1) * 64;
  const int l15  = lane & 15, l4 = lane >> 4;
  const int ls   = lane & 7, lr = lane >> 3;
  const int gch  = ls ^ lr;

  const char* aSrc[4];
  const char* bSrc[4];
  unsigned short* aDst[4];
  unsigned short* bDst[4];
#pragma unroll
  for (int i = 0; i < 4; ++i) {
    int r = w * 32 + i * 8 + lr;
    aSrc[i] = (const char*)xb + (size_t)tIdx[r] * 1024 + gch * 16;
    bSrc[i] = (const char*)bm + ((size_t)e * 512 + fn * 128 + r) * 1024 +
              gch * 16;
    aDst[i] = As + (w * 32 + i * 8) * 64 + lane * 8;
    bDst[i] = Bs + (w * 32 + i * 8) * 64 + lane * 8;
  }

  f32x4 acc[4][4];
#pragma unroll
  for (int m = 0; m < 4; ++m)
#pragma unroll
    for (int n = 0; n < 4; ++n) acc[m][n] = (f32x4){0.f, 0.f, 0.f, 0.f};

  for (int kk = 0; kk < J; kk += 64) {
#pragma unroll
    for (int i = 0; i < 4; ++i) {
      gl16(aSrc[i] + kk * 2, aDst[i]);
      gl16(bSrc[i] + kk * 2, bDst[i]);
    }
    __syncthreads();
#pragma unroll
    for (int kk2 = 0; kk2 < 2; ++kk2) {
      bf16x8 af[4], bfr[4];
#pragma unroll
      for (int m = 0; m < 4; ++m) {
        int r = wr + m * 16 + l15;
        int s = (kk2 * 4 + l4) ^ (r & 7);
        af[m] = *(const bf16x8*)(&As[r * 64 + s * 8]);
      }
#pragma unroll
      for (int n = 0; n < 4; ++n) {
        int cl = wc + n * 16 + l15;
        int s = (kk2 * 4 + l4) ^ (cl & 7);
        bfr[n] = *(const bf16x8*)(&Bs[cl * 64 + s * 8]);
      }
#pragma unroll
      for (int m = 0; m < 4; ++m)
#pragma unroll
        for (int n = 0; n < 4; ++n)
          acc[m][n] = __builtin_amdgcn_mfma_f32_16x16x32_bf16(
              af[m], bfr[n], acc[m][n], 0, 0, 0);
    }
    __syncthreads();
  }

#pragma unroll
  for (int m = 0; m < 4; ++m) {
#pragma unroll
    for (int q = 0; q < 4; ++q) {
      int rl = wr + m * 16 + l4 * 4 + q;
      int t = tIdx[rl];
      float wv = wRow[rl];
      float* dst = out + (size_t)t * J + fn * 128 + wc + l15;
#pragma unroll
      for (int n = 0; n < 4; ++n)
        atomicAdd(dst + n * 16, acc[m][n][q] * wv);
    }
  }
}

// ---------------------------------------------------------------------------
// K5 (tier-2 fallback): res = gelu(out/max(cnt,1)+bias), in place.
// ---------------------------------------------------------------------------
__global__ __launch_bounds__(256)
void k5_final(float* __restrict__ res, const float* __restrict__ cnt,
              const float* __restrict__ bias) {
  const int total4 = BT * J / 4;
  for (int i = blockIdx.x * blockDim.x + threadIdx.x; i < total4;
       i += gridDim.x * blockDim.x) {
    float4 v = reinterpret_cast<float4*>(res)[i];
    int base = i << 2;
    int t = base >> 9;
    int col = base & 511;
    float inv = 1.0f / fmaxf(cnt[t], 1.0f);
    int f0 = col >> 1;
    float b0 = bias[f0], b1 = bias[f0 + 1];
    float h0 = v.x * inv + b0;
    float h1 = v.y * inv + b0;
    float h2 = v.z * inv + b1;
    float h3 = v.w * inv + b1;
    const float is2 = 0.70710678118654752f;
    v.x = 0.5f * h0 * (1.0f + erff(h0 * is2));
    v.y = 0.5f * h1 * (1.0f + erff(h1 * is2));
    v.z = 0.5f * h2 * (1.0f + erff(h2 * is2));
    v.w = 0.5f * h3 * (1.0f + erff(h3 * is2));
    reinterpret_cast<float4*>(res)[i] = v;
  }
}

// ---------------------------------------------------------------------------
extern "C" void kernel_launch(void* const* d_in, const int* in_sizes, int n_in,
                              void* d_out, int out_size, void* d_ws,
                              size_t ws_size, hipStream_t stream) {
  const float* x    = (const float*)d_in[0];
  const float* gw   = (const float*)d_in[1];
  const float* ew   = (const float*)d_in[2];
  const float* bias = (const float*)d_in[3];

  float* out_f = (float*)d_out;
  float* res   = out_f;
  float* o_idx = out_f + OFF_IDX;
  float* o_scr = out_f + OFF_SCR;
  float* o_cnt = out_f + OFF_CNT;

  // Borrowed regions inside res (all rewritten later by k5g/k5):
  //   scoresT @ 0 (16.8 MB) | parts @ 32 MB | thr12 @ 36 MB |
  //   cand @ 48 MB (2 MB) | ccnt @ 52 MB
  float*              scoresT = res;
  unsigned*           parts   = (unsigned*)((char*)res + (size_t)32 * 1024 * 1024);
  unsigned*           thr12   = (unsigned*)((char*)res + (size_t)36 * 1024 * 1024);
  unsigned long long* cand    = (unsigned long long*)((char*)res + (size_t)48 * 1024 * 1024);
  int*                ccnt    = (int*)((char*)res + (size_t)52 * 1024 * 1024);

  unsigned short* xb  = (unsigned short*)((char*)d_ws + WS_XB);
  unsigned short* bm  = (unsigned short*)((char*)d_ws + WS_BM);
  unsigned short* yD  = (unsigned short*)((char*)d_ws + WS_YD);
  int*            cur = (int*)((char*)d_ws + WS_CUR);
  int*            slt = (int*)((char*)d_ws + WS_SLOT);

  const bool tier1 = (ws_size >= WS_NEED1);
  const bool tier2 = (ws_size >= WS_NEED2);

  // k3b fused into k1 (tier-1/2); standalone launch no longer needed.
  k1_scores<<<BT / 64, 256, 0, stream>>>(x, gw, scoresT,
                                         tier2 ? xb : nullptr, ew,
                                         tier2 ? bm : nullptr);
  k2a_hist<<<E * 4, 1024, 0, stream>>>(scoresT, parts, o_cnt,
                                       tier1 ? cur : nullptr);
  k2b_scan<<<E, 256, 0, stream>>>(parts, thr12, ccnt);
  k2c_collect<<<E * 4, 1024, 0, stream>>>(scoresT, thr12, cand, ccnt);
  k2d_sort<<<E, 1024, 0, stream>>>(cand, ccnt, o_idx, o_scr, o_cnt,
                                   tier1 ? cur : nullptr,
                                   tier1 ? slt : nullptr);
  if (tier1) {
    k4c_mfma<<<4096, 256, 0, stream>>>(xb, bm, o_idx, o_scr, yD);
    k5g<<<BT / 4, 256, 0, stream>>>(yD, cur, slt, bias, res);
  } else if (tier2) {
    hipMemsetAsync(res, 0, (size_t)BT * J * sizeof(float), stream);
    k4b_mfma<<<dim3(4, 16, E), 256, 0, stream>>>(xb, bm, o_idx, o_scr, res);
    k5_final<<<8192, 256, 0, stream>>>(res, o_cnt, bias);
  }
}

// Round 23
// 348.454 us; speedup vs baseline: 1.0954x; 1.0024x over previous
//
#include <hip/hip_runtime.h>
#include <hip/hip_fp16.h>
#include <math.h>

constexpr int BT = 65536;
constexpr int D  = 256;
constexpr int E  = 64;
constexpr int K  = 2048;
constexpr int J  = 512; // 2*D

// d_out layout (floats): res | topk_idx | topk_scores | counts
constexpr size_t OFF_IDX = (size_t)BT * D * 2;       // 33,554,432
constexpr size_t OFF_SCR = OFF_IDX + (size_t)E * K;  // +131,072
constexpr size_t OFF_CNT = OFF_SCR + (size_t)E * K;  // +131,072

// d_ws layout (bytes):
//   xb   bf16[BT][512]        @ 0          (64 MiB)
//   bm   bf16[E][512][512]    @ 64 MiB     (32 MiB)
//   yD   fp16[E*K][512]       @ 96 MiB     (128 MiB)   [tier-1 only]
//   cur  int[BT]              @ 224 MiB    (256 KiB)   [tier-1 only]
//   slot int[BT][32]          @ 224.25 MiB (8 MiB)     [tier-1 only]
constexpr size_t WS_XB    = 0;
constexpr size_t WS_BM    = 67108864;
constexpr size_t WS_YD    = 100663296;
constexpr size_t WS_CUR   = 234881024;
constexpr size_t WS_SLOT  = 235143168;
constexpr size_t WS_NEED1 = 243531776;              // tier-1: full path
constexpr size_t WS_NEED2 = 100663296;              // tier-2 path
constexpr int    SLOT_PAD = 32;

typedef __attribute__((ext_vector_type(8))) short bf16x8;
typedef __attribute__((ext_vector_type(4))) float f32x4;
typedef __attribute__((ext_vector_type(4))) unsigned int u32x4;

__device__ __forceinline__ unsigned short f2bf(float f) {
  unsigned u = __float_as_uint(f);
  u = (u + 0x7FFFu + ((u >> 16) & 1u)) >> 16;  // RTNE
  return (unsigned short)u;
}

__device__ __forceinline__ void gl16(const void* g, void* l) {
  __builtin_amdgcn_global_load_lds(
      (const __attribute__((address_space(1))) unsigned int*)g,
      (__attribute__((address_space(3))) unsigned int*)l, 16, 0, 0);
}

__device__ __forceinline__ unsigned fkey(float s) {
  unsigned u = __float_as_uint(s);
  return (u & 0x80000000u) ? ~u : (u | 0x80000000u);
}

// ---------------------------------------------------------------------------
// K1 (v5 = v4 with COALESCED fused-k3b decode): scoresT[e][t] = fp32 dot as
// ONE sequential FMA chain j=0..511 (bit-matches np's sgemm — UNCHANGED).
// 64-token blocks (grid 1024), thread tile 4 tok x 4 exp, b128 LDS reads,
// NT x loads, fused bf16 xb emit.
// Fused Bmat emit (new decode): block covers e = bid>>4 and a 4-aligned sub
// group sb..sb+3; lanes take consecutive n -> ew reads are 256B-contiguous
// per wave (coalesced); bm writes are 1KB-strided 16B but each 64B line is
// completed by one block (L2 write-combine merges; regular stores keep bm
// L2-resident for k4c's 16x reuse). Values bit-identical to k3b.
// ---------------------------------------------------------------------------
__global__ __launch_bounds__(256)
void k1_scores(const float* __restrict__ x, const float* __restrict__ gw,
               float* __restrict__ scoresT, unsigned short* __restrict__ xbp,
               const float* __restrict__ ew, unsigned short* __restrict__ bmp) {
  __shared__ float xs[64][68];    // 17.4 KB
  __shared__ float gsT[64][68];   // 17.4 KB
  const int t0 = blockIdx.x * 64;
  const int tid = threadIdx.x;
  const int tx = tid & 15;   // token sub-index (4 tokens: a*16+tx)
  const int ty = tid >> 4;   // expert group (4 experts: ty*4+b)
  float acc[4][4] = {};

  for (int kk = 0; kk < 8; ++kk) {
    // ---- stage x (float4 coalesced, NT) + fused bf16 emit
#pragma unroll
    for (int i = 0; i < 4; ++i) {
      int idx = tid + 256 * i;
      int r = idx >> 4, c4 = (idx & 15) * 4;
      f32x4 v = __builtin_nontemporal_load(
          (const f32x4*)(&x[(size_t)(t0 + r) * J + kk * 64 + c4]));
      *(f32x4*)(&xs[r][c4]) = v;
      if (xbp) {
        uint2 u;
        u.x = (unsigned)f2bf(v.x) | ((unsigned)f2bf(v.y) << 16);
        u.y = (unsigned)f2bf(v.z) | ((unsigned)f2bf(v.w) << 16);
        *(uint2*)(&xbp[(size_t)(t0 + r) * J + kk * 64 + c4]) = u;
      }
    }
    // ---- stage gw transposed: gsT[e][j]
#pragma unroll
    for (int i = 0; i < 4; ++i) {
      int idx = tid + 256 * i;
      int r = idx >> 4, c4 = (idx & 15) * 4;   // r = j-local, c4 = expert
      float4 v = *(const float4*)(&gw[(size_t)(kk * 64 + r) * E + c4]);
      gsT[c4][r]     = v.x;
      gsT[c4 + 1][r] = v.y;
      gsT[c4 + 2][r] = v.z;
      gsT[c4 + 3][r] = v.w;
    }
    __syncthreads();
    // ---- compute: j in groups of 4, b128 reads, chain order preserved
#pragma unroll 4
    for (int j = 0; j < 64; j += 4) {
      float4 xv[4], gv[4];
#pragma unroll
      for (int a = 0; a < 4; ++a)
        xv[a] = *(const float4*)(&xs[a * 16 + tx][j]);
#pragma unroll
      for (int b = 0; b < 4; ++b)
        gv[b] = *(const float4*)(&gsT[ty * 4 + b][j]);
#define K1_FMA(COMP)                                                        \
  _Pragma("unroll") for (int a = 0; a < 4; ++a)                             \
    _Pragma("unroll") for (int b = 0; b < 4; ++b)                           \
      acc[a][b] = fmaf(xv[a].COMP, gv[b].COMP, acc[a][b]);
      K1_FMA(x) K1_FMA(y) K1_FMA(z) K1_FMA(w)
#undef K1_FMA
    }
    __syncthreads();
  }

#pragma unroll
  for (int b = 0; b < 4; ++b) {
    int e = ty * 4 + b;
#pragma unroll
    for (int a = 0; a < 4; ++a)
      scoresT[(size_t)e * BT + t0 + a * 16 + tx] = acc[a][b];
  }

  // ---- fused k3b slice (coalesced decode):
  // Bmat[e][n=2f+co][k=2d+ci] = bf16(ew[e][d][f][ci^co] * sign)
  if (bmp) {
    const int be = blockIdx.x >> 4;          // expert
    const int sb = (blockIdx.x & 15) * 4;    // 4-aligned sub (k-octet) base
#pragma unroll
    for (int i = 0; i < 8; ++i) {
      int sub = sb + (i >> 1);               // k-octet 0..63
      int n   = ((i & 1) << 8) + tid;        // 0..511, lane-consecutive
      int f   = n >> 1, co = n & 1;
      int d0  = sub * 4;
      const float* wb = ew + (((size_t)be * 256) * 256 + f) * 2;
      union { unsigned short h[8]; bf16x8 v; } pk;
#pragma unroll
      for (int dd = 0; dd < 4; ++dd) {
        float2 wv = *(const float2*)(wb + (size_t)(d0 + dd) * 512);
        float b0 = co ? wv.y : wv.x;         // ci=0
        float b1 = co ? wv.x : -wv.y;        // ci=1
        pk.h[dd * 2]     = f2bf(b0);
        pk.h[dd * 2 + 1] = f2bf(b1);
      }
      ((bf16x8*)bmp)[((size_t)be << 15) + (size_t)n * 64 + sub] = pk.v;
    }
  }
}

// ---------------------------------------------------------------------------
// K2a: 12-bit-key histogram, 4 blocks/expert, 8-way privatized LDS, then a
// NON-atomic partial write to parts[bid][4096].
// Fused: zeros o_cnt and cur (256 blocks x 1024 threads == BT exactly).
// ---------------------------------------------------------------------------
__global__ __launch_bounds__(1024)
void k2a_hist(const float* __restrict__ scoresT, unsigned* __restrict__ parts,
              float* __restrict__ o_cnt, int* __restrict__ cur) {
  const int bid = blockIdx.x;          // e*4 + q
  const int tid = threadIdx.x;
  const int g   = bid * 1024 + tid;    // 0 .. BT-1
  o_cnt[g] = 0.0f;
  if (cur) cur[g] = 0;
  __shared__ unsigned h[8][4096];      // 128 KiB, 8-way privatization
  for (int i = tid; i < 8 * 4096; i += 1024) ((unsigned*)h)[i] = 0u;
  __syncthreads();
  const int copy = tid >> 7;           // 2 waves share a copy
  const float4* src = (const float4*)(scoresT + ((size_t)bid << 14));
#pragma unroll
  for (int it = 0; it < 4; ++it) {
    float4 v = src[it * 1024 + tid];
    atomicAdd(&h[copy][fkey(v.x) >> 20], 1u);
    atomicAdd(&h[copy][fkey(v.y) >> 20], 1u);
    atomicAdd(&h[copy][fkey(v.z) >> 20], 1u);
    atomicAdd(&h[copy][fkey(v.w) >> 20], 1u);
  }
  __syncthreads();
  unsigned* dst = parts + ((size_t)bid << 12);
  for (int j = tid; j < 4096; j += 1024) {
    unsigned s = 0;
#pragma unroll
    for (int c = 0; c < 8; ++c) s += h[c][j];
    dst[j] = s;
  }
}

// ---------------------------------------------------------------------------
// K2b: per-expert descending scan over summed parts -> 12-bit bucket of the
// rank-K key. Fused: zeros ccnt[e].
// ---------------------------------------------------------------------------
__global__ __launch_bounds__(256)
void k2b_scan(const unsigned* __restrict__ parts, unsigned* __restrict__ thr12,
              int* __restrict__ ccnt) {
  const int e = blockIdx.x;
  const unsigned* p = parts + ((size_t)e << 14);  // 4 parts x 4096
  __shared__ unsigned chs[256];
  const int tid = threadIdx.x;
  if (tid == 0) ccnt[e] = 0;
  const int lo = 4095 - tid * 16 - 15;  // chunk tid covers [lo, lo+15] desc
  unsigned s = 0;
  for (int j = 0; j < 16; ++j) {
    int b = lo + j;
    s += p[b] + p[4096 + b] + p[8192 + b] + p[12288 + b];
  }
  chs[tid] = s;
  __syncthreads();
  if (tid == 0) {
    unsigned cum = 0; int c = 0;
    for (; c < 255; ++c) {
      if (cum + chs[c] >= (unsigned)K) break;
      cum += chs[c];
    }
    int vb = 4095 - c * 16;
    unsigned b = 0;
    for (int j = 0; j < 16; ++j) {
      int bb = vb - j;
      cum += p[bb] + p[4096 + bb] + p[8192 + bb] + p[12288 + bb];
      if (cum >= (unsigned)K) { b = (unsigned)bb; break; }
    }
    thr12[e] = b;
  }
}

// ---------------------------------------------------------------------------
// K2c: parallel collect, 4 blocks/expert. LDS-local cursor; ONE global
// atomic per block reserves a segment of cand[e]; coalesced flush.
// NT loads: k2c is the LAST reader of scoresT.
// ---------------------------------------------------------------------------
__global__ __launch_bounds__(1024)
void k2c_collect(const float* __restrict__ scoresT,
                 const unsigned* __restrict__ thr12,
                 unsigned long long* __restrict__ cand,
                 int* __restrict__ ccnt) {
  const int bid = blockIdx.x;  // e*4 + q
  const int e = bid >> 2;
  const unsigned bthr = thr12[e] << 20;
  const float* row = scoresT + ((size_t)bid << 14);
  const unsigned ibase = (unsigned)(bid & 3) << 14;
  __shared__ int sh_n, sh_base;
  __shared__ unsigned long long lkeys[4096];
  const int tid = threadIdx.x;
  if (tid == 0) sh_n = 0;
  __syncthreads();
  for (int i = tid; i < 16384; i += 1024) {
    float sv = __builtin_nontemporal_load(&row[i]);
    unsigned u = fkey(sv);
    if (u >= bthr) {
      int pos = atomicAdd(&sh_n, 1);   // LDS atomic
      if (pos < 4096)
        lkeys[pos] =
            ((unsigned long long)u << 32) | (unsigned)(~(ibase + i));
    }
  }
  __syncthreads();
  int n = sh_n; if (n > 4096) n = 4096;
  if (tid == 0) sh_base = atomicAdd(&ccnt[e], n);  // one global atomic/block
  __syncthreads();
  const int base = sh_base;
  for (int i = tid; i < n; i += 1024)
    if (base + i < 4096) cand[((size_t)e << 12) + base + i] = lkeys[i];
}

// ---------------------------------------------------------------------------
// K2d: per-expert bitonic sort of candidates (score desc, idx asc) + output
// tail. Comparator network is order-canonical -> bit-identical results.
// NT loads for cand (read-once).
// ---------------------------------------------------------------------------
__global__ __launch_bounds__(1024)
void k2d_sort(const unsigned long long* __restrict__ cand,
              const int* __restrict__ ccnt,
              float* __restrict__ o_idx, float* __restrict__ o_scr,
              float* __restrict__ o_cnt,
              int* __restrict__ cur, int* __restrict__ slots) {
  const int e = blockIdx.x;
  __shared__ unsigned long long keys[4096];
  const int tid = threadIdx.x;
  int n = ccnt[e]; if (n > 4096) n = 4096;
  for (int i = tid; i < 4096; i += 1024)
    keys[i] = (i < n)
        ? __builtin_nontemporal_load(&cand[((size_t)e << 12) + i])
        : 0ull;
  __syncthreads();
  for (int kk = 2; kk <= 4096; kk <<= 1) {
    for (int j = kk >> 1; j > 0; j >>= 1) {
      for (int i = tid; i < 4096; i += 1024) {
        int ij = i ^ j;
        if (ij > i) {
          bool up = ((i & kk) == 0);
          unsigned long long a = keys[i], b = keys[ij];
          if ((a < b) == up) { keys[i] = b; keys[ij] = a; }
        }
      }
      __syncthreads();
    }
  }
  for (int r = tid; r < K; r += 1024) {
    unsigned long long kv = keys[r];
    unsigned u = (unsigned)(kv >> 32);
    unsigned idx = ~((unsigned)kv);
    float s = __uint_as_float((u & 0x80000000u) ? (u ^ 0x80000000u) : ~u);
    o_idx[(size_t)e * K + r] = (float)idx;
    o_scr[(size_t)e * K + r] = s;
    atomicAdd(&o_cnt[idx], 1.0f);
    if (slots) {
      int pos = atomicAdd(&cur[idx], 1);
      if (pos < SLOT_PAD) slots[(size_t)idx * SLOT_PAD + pos] = e * K + r;
    }
  }
}

// ---------------------------------------------------------------------------
// K4c (tier-1, v8): MFMA bf16 GEMM, dense fp16 output (NO atomics).
// 128x128 tile, BK=64, 2-phase double-buffered LDS, setprio(1) around MFMA
// cluster (T5, +13% measured), NT yD stores (write-once stream).
// ---------------------------------------------------------------------------
__global__ __launch_bounds__(256)
void k4c_mfma(const unsigned short* __restrict__ xb,
              const unsigned short* __restrict__ bm,
              const float* __restrict__ o_idx, const float* __restrict__ o_scr,
              unsigned short* __restrict__ yD) {
  const int bid = blockIdx.x;
  const int xcd = bid & 7;
  const int s   = bid >> 3;
  const int fn  = s & 3;
  const int km  = (s >> 2) & 15;
  const int e   = xcd + ((s >> 6) << 3);

  // sh: A dbuf = sh + cb*8192 (each 128 rows x 64 shorts);
  //     B dbuf = sh + 16384 + cb*8192. Pk overlay @0 (17408 shorts).
  __shared__ __align__(16) unsigned short sh[32768];
  __shared__ int   tIdx[128];
  __shared__ float wRow[128];
  const int tid = threadIdx.x;
  if (tid < 128) {
    size_t gi = (size_t)e * K + km * 128 + tid;
    tIdx[tid] = (int)o_idx[gi];
    wRow[tid] = o_scr[gi];
  }
  __syncthreads();

  const int lane = tid & 63;
  const int w    = tid >> 6;
  const int wr   = (w & 1) * 64;
  const int wc   = (w >> 1) * 64;
  const int l15  = lane & 15, l4 = lane >> 4;
  const int ls   = lane & 7, lr = lane >> 3;
  const int gch  = ls ^ lr;  // pre-swizzled source chunk (row&7 == lr)

  // per-lane global source bases and LDS dest offsets (shorts) per row-octet
  const char* aSrc[4];
  const char* bSrc[4];
  int dstOff[4];
#pragma unroll
  for (int i = 0; i < 4; ++i) {
    int r = w * 32 + i * 8 + lr;
    aSrc[i] = (const char*)xb + (size_t)tIdx[r] * 1024 + gch * 16;
    bSrc[i] = (const char*)bm + ((size_t)e * 512 + fn * 128 + r) * 1024 +
              gch * 16;
    dstOff[i] = (w * 32 + i * 8) * 64 + lane * 8;
  }

  f32x4 acc[4][4];
#pragma unroll
  for (int m = 0; m < 4; ++m)
#pragma unroll
    for (int n = 0; n < 4; ++n) acc[m][n] = (f32x4){0.f, 0.f, 0.f, 0.f};

  // prologue: K-step 0 into buffer 0
#pragma unroll
  for (int i = 0; i < 4; ++i) {
    gl16(aSrc[i], sh + dstOff[i]);
    gl16(bSrc[i], sh + 16384 + dstOff[i]);
  }

#pragma unroll
  for (int t = 0; t < 8; ++t) {
    const int cb = t & 1;
    __syncthreads();  // drains vmcnt -> buffer cb ready
    if (t < 7) {      // stage next tile into cb^1 while computing cb
      const int nxt = (cb ^ 1) * 8192;
#pragma unroll
      for (int i = 0; i < 4; ++i) {
        gl16(aSrc[i] + (t + 1) * 128, sh + nxt + dstOff[i]);
        gl16(bSrc[i] + (t + 1) * 128, sh + 16384 + nxt + dstOff[i]);
      }
    }
    const unsigned short* Ab = sh + cb * 8192;
    const unsigned short* Bb = sh + 16384 + cb * 8192;
#pragma unroll
    for (int kk2 = 0; kk2 < 2; ++kk2) {
      bf16x8 af[4], bfr[4];
#pragma unroll
      for (int m = 0; m < 4; ++m) {
        int r = wr + m * 16 + l15;
        int sw = (kk2 * 4 + l4) ^ (r & 7);
        af[m] = *(const bf16x8*)(&Ab[r * 64 + sw * 8]);
      }
#pragma unroll
      for (int n = 0; n < 4; ++n) {
        int cl = wc + n * 16 + l15;
        int sw = (kk2 * 4 + l4) ^ (cl & 7);
        bfr[n] = *(const bf16x8*)(&Bb[cl * 64 + sw * 8]);
      }
      __builtin_amdgcn_s_setprio(1);
#pragma unroll
      for (int m = 0; m < 4; ++m)
#pragma unroll
        for (int n = 0; n < 4; ++n)
          acc[m][n] = __builtin_amdgcn_mfma_f32_16x16x32_bf16(
              af[m], bfr[n], acc[m][n], 0, 0, 0);
      __builtin_amdgcn_s_setprio(0);
    }
  }

  // epilogue: weight, fp16-pack via padded-LDS repack (stride 136), NT store
  __syncthreads();
  unsigned short* Pk = sh;  // 128 x 136 = 17408 shorts (fits in 32768)
#pragma unroll
  for (int m = 0; m < 4; ++m) {
#pragma unroll
    for (int q = 0; q < 4; ++q) {
      int row = wr + m * 16 + l4 * 4 + q;
      float wv = wRow[row];
#pragma unroll
      for (int n = 0; n < 4; ++n) {
        int col = wc + n * 16 + l15;
        Pk[row * 136 + col] =
            __half_as_ushort(__float2half(acc[m][n][q] * wv));
      }
    }
  }
  __syncthreads();
  const size_t rowBase = (size_t)e * K + km * 128;
#pragma unroll
  for (int i = 0; i < 8; ++i) {
    int c2 = tid + 256 * i;
    int row = c2 >> 4, ch = c2 & 15;
    u32x4 v = *(const u32x4*)(&Pk[row * 136 + ch * 8]);
    __builtin_nontemporal_store(
        v, (u32x4*)(yD + (rowBase + row) * 512 + fn * 128 + ch * 8));
  }
}

// ---------------------------------------------------------------------------
// K5g (tier-1): per-token gather-finalize (one wave per token).
// NT loads for yD (read-once) and NT stores for res (write-once).
// ---------------------------------------------------------------------------
__global__ __launch_bounds__(256)
void k5g(const unsigned short* __restrict__ yD, const int* __restrict__ cur,
         const int* __restrict__ slots, const float* __restrict__ bias,
         float* __restrict__ res) {
  const int t    = blockIdx.x * 4 + (threadIdx.x >> 6);
  const int lane = threadIdx.x & 63;
  const int nc   = cur[t];
  const int ncc  = nc < SLOT_PAD ? nc : SLOT_PAD;
  float acc[8] = {};
  const int* sl = slots + (size_t)t * SLOT_PAD;
  for (int c = 0; c < ncc; ++c) {
    int slot = sl[c];
    union { u32x4 v; unsigned short h[8]; } U;
    U.v = __builtin_nontemporal_load(
        (const u32x4*)(yD + (size_t)slot * 512 + lane * 8));
#pragma unroll
    for (int j = 0; j < 8; ++j)
      acc[j] += __half2float(__ushort_as_half(U.h[j]));
  }
  const float inv = 1.0f / fmaxf((float)nc, 1.0f);
  float4 b4 = *(const float4*)(bias + lane * 4);
  const float* bp = (const float*)&b4;
  const float is2 = 0.70710678118654752f;
  float r8[8];
#pragma unroll
  for (int j = 0; j < 8; ++j) {
    float h = acc[j] * inv + bp[j >> 1];
    r8[j] = 0.5f * h * (1.0f + erff(h * is2));
  }
  float* dst = res + (size_t)t * J + lane * 8;
  f32x4 lo = (f32x4){r8[0], r8[1], r8[2], r8[3]};
  f32x4 hi = (f32x4){r8[4], r8[5], r8[6], r8[7]};
  __builtin_nontemporal_store(lo, (f32x4*)dst);
  __builtin_nontemporal_store(hi, (f32x4*)(dst + 4));
}

// ---------------------------------------------------------------------------
// K3b (tier-2 fallback only): Bmat[e][n][k] = bf16( ew * sign ).
// ---------------------------------------------------------------------------
__global__ __launch_bounds__(256)
void k3b_bmat(const float* __restrict__ ew, unsigned short* __restrict__ bm) {
  int id = blockIdx.x * 256 + threadIdx.x;
  int sub = id & 63;
  int ng  = id >> 6;
  int e   = ng >> 9;
  int n   = ng & 511;
  int f   = n >> 1, co = n & 1;
  int d0  = sub * 4;
  const float* wb = ew + (((size_t)e * 256) * 256 + f) * 2;
  union { unsigned short h[8]; bf16x8 v; } pk;
#pragma unroll
  for (int dd = 0; dd < 4; ++dd) {
    float2 wv = *(const float2*)(wb + (size_t)(d0 + dd) * 512);
    float b0 = co ? wv.y : wv.x;
    float b1 = co ? wv.x : -wv.y;
    pk.h[dd * 2]     = f2bf(b0);
    pk.h[dd * 2 + 1] = f2bf(b1);
  }
  ((bf16x8*)bm)[id] = pk.v;
}

// ---------------------------------------------------------------------------
// K4b (tier-2 fallback): atomic-scatter MFMA GEMM (round-7 verified).
// ---------------------------------------------------------------------------
__global__ __launch_bounds__(256)
void k4b_mfma(const unsigned short* __restrict__ xb,
              const unsigned short* __restrict__ bm,
              const float* __restrict__ o_idx, const float* __restrict__ o_scr,
              float* __restrict__ out) {
  const int e  = blockIdx.z;
  const int km = blockIdx.y;
  const int fn = blockIdx.x;
  __shared__ __align__(16) unsigned short As[128 * 64];
  __shared__ __align__(16) unsigned short Bs[128 * 64];
  __shared__ int   tIdx[128];
  __shared__ float wRow[128];
  const int tid = threadIdx.x;
  if (tid < 128) {
    size_t gi = (size_t)e * K + km * 128 + tid;
    tIdx[tid] = (int)o_idx[gi];
    wRow[tid] = o_scr[gi];
  }
  __syncthreads();

  const int lane = tid & 63;
  const int w    = tid >> 6;
  const int wr   = (w & 1) * 64;
  const int wc   = (w >> 1) * 64;
  const int l15  = lane & 15, l4 = lane >> 4;
  const int ls   = lane & 7, lr = lane >> 3;
  const int gch  = ls ^ lr;

  const char* aSrc[4];
  const char* bSrc[4];
  unsigned short* aDst[4];
  unsigned short* bDst[4];
#pragma unroll
  for (int i = 0; i < 4; ++i) {
    int r = w * 32 + i * 8 + lr;
    aSrc[i] = (const char*)xb + (size_t)tIdx[r] * 1024 + gch * 16;
    bSrc[i] = (const char*)bm + ((size_t)e * 512 + fn * 128 + r) * 1024 +
              gch * 16;
    aDst[i] = As + (w * 32 + i * 8) * 64 + lane * 8;
    bDst[i] = Bs + (w * 32 + i * 8) * 64 + lane * 8;
  }

  f32x4 acc[4][4];
#pragma unroll
  for (int m = 0; m < 4; ++m)
#pragma unroll
    for (int n = 0; n < 4; ++n) acc[m][n] = (f32x4){0.f, 0.f, 0.f, 0.f};

  for (int kk = 0; kk < J; kk += 64) {
#pragma unroll
    for (int i = 0; i < 4; ++i) {
      gl16(aSrc[i] + kk * 2, aDst[i]);
      gl16(bSrc[i] + kk * 2, bDst[i]);
    }
    __syncthreads();
#pragma unroll
    for (int kk2 = 0; kk2 < 2; ++kk2) {
      bf16x8 af[4], bfr[4];
#pragma unroll
      for (int m = 0; m < 4; ++m) {
        int r = wr + m * 16 + l15;
        int s = (kk2 * 4 + l4) ^ (r & 7);
        af[m] = *(const bf16x8*)(&As[r * 64 + s * 8]);
      }
#pragma unroll
      for (int n = 0; n < 4; ++n) {
        int cl = wc + n * 16 + l15;
        int s = (kk2 * 4 + l4) ^ (cl & 7);
        bfr[n] = *(const bf16x8*)(&Bs[cl * 64 + s * 8]);
      }
#pragma unroll
      for (int m = 0; m < 4; ++m)
#pragma unroll
        for (int n = 0; n < 4; ++n)
          acc[m][n] = __builtin_amdgcn_mfma_f32_16x16x32_bf16(
              af[m], bfr[n], acc[m][n], 0, 0, 0);
    }
    __syncthreads();
  }

#pragma unroll
  for (int m = 0; m < 4; ++m) {
#pragma unroll
    for (int q = 0; q < 4; ++q) {
      int rl = wr + m * 16 + l4 * 4 + q;
      int t = tIdx[rl];
      float wv = wRow[rl];
      float* dst = out + (size_t)t * J + fn * 128 + wc + l15;
#pragma unroll
      for (int n = 0; n < 4; ++n)
        atomicAdd(dst + n * 16, acc[m][n][q] * wv);
    }
  }
}

// ---------------------------------------------------------------------------
// K5 (tier-2 fallback): res = gelu(out/max(cnt,1)+bias), in place.
// ---------------------------------------------------------------------------
__global__ __launch_bounds__(256)
void k5_final(float* __restrict__ res, const float* __restrict__ cnt,
              const float* __restrict__ bias) {
  const int total4 = BT * J / 4;
  for (int i = blockIdx.x * blockDim.x + threadIdx.x; i < total4;
       i += gridDim.x * blockDim.x) {
    float4 v = reinterpret_cast<float4*>(res)[i];
    int base = i << 2;
    int t = base >> 9;
    int col = base & 511;
    float inv = 1.0f / fmaxf(cnt[t], 1.0f);
    int f0 = col >> 1;
    float b0 = bias[f0], b1 = bias[f0 + 1];
    float h0 = v.x * inv + b0;
    float h1 = v.y * inv + b0;
    float h2 = v.z * inv + b1;
    float h3 = v.w * inv + b1;
    const float is2 = 0.70710678118654752f;
    v.x = 0.5f * h0 * (1.0f + erff(h0 * is2));
    v.y = 0.5f * h1 * (1.0f + erff(h1 * is2));
    v.z = 0.5f * h2 * (1.0f + erff(h2 * is2));
    v.w = 0.5f * h3 * (1.0f + erff(h3 * is2));
    reinterpret_cast<float4*>(res)[i] = v;
  }
}

// ---------------------------------------------------------------------------
extern "C" void kernel_launch(void* const* d_in, const int* in_sizes, int n_in,
                              void* d_out, int out_size, void* d_ws,
                              size_t ws_size, hipStream_t stream) {
  const float* x    = (const float*)d_in[0];
  const float* gw   = (const float*)d_in[1];
  const float* ew   = (const float*)d_in[2];
  const float* bias = (const float*)d_in[3];

  float* out_f = (float*)d_out;
  float* res   = out_f;
  float* o_idx = out_f + OFF_IDX;
  float* o_scr = out_f + OFF_SCR;
  float* o_cnt = out_f + OFF_CNT;

  // Borrowed regions inside res (all rewritten later by k5g/k5):
  //   scoresT @ 0 (16.8 MB) | parts @ 32 MB | thr12 @ 36 MB |
  //   cand @ 48 MB (2 MB) | ccnt @ 52 MB
  float*              scoresT = res;
  unsigned*           parts   = (unsigned*)((char*)res + (size_t)32 * 1024 * 1024);
  unsigned*           thr12   = (unsigned*)((char*)res + (size_t)36 * 1024 * 1024);
  unsigned long long* cand    = (unsigned long long*)((char*)res + (size_t)48 * 1024 * 1024);
  int*                ccnt    = (int*)((char*)res + (size_t)52 * 1024 * 1024);

  unsigned short* xb  = (unsigned short*)((char*)d_ws + WS_XB);
  unsigned short* bm  = (unsigned short*)((char*)d_ws + WS_BM);
  unsigned short* yD  = (unsigned short*)((char*)d_ws + WS_YD);
  int*            cur = (int*)((char*)d_ws + WS_CUR);
  int*            slt = (int*)((char*)d_ws + WS_SLOT);

  const bool tier1 = (ws_size >= WS_NEED1);
  const bool tier2 = (ws_size >= WS_NEED2);

  // k3b fused into k1 (tier-1/2); standalone launch no longer needed.
  k1_scores<<<BT / 64, 256, 0, stream>>>(x, gw, scoresT,
                                         tier2 ? xb : nullptr, ew,
                                         tier2 ? bm : nullptr);
  k2a_hist<<<E * 4, 1024, 0, stream>>>(scoresT, parts, o_cnt,
                                       tier1 ? cur : nullptr);
  k2b_scan<<<E, 256, 0, stream>>>(parts, thr12, ccnt);
  k2c_collect<<<E * 4, 1024, 0, stream>>>(scoresT, thr12, cand, ccnt);
  k2d_sort<<<E, 1024, 0, stream>>>(cand, ccnt, o_idx, o_scr, o_cnt,
                                   tier1 ? cur : nullptr,
                                   tier1 ? slt : nullptr);
  if (tier1) {
    k4c_mfma<<<4096, 256, 0, stream>>>(xb, bm, o_idx, o_scr, yD);
    k5g<<<BT / 4, 256, 0, stream>>>(yD, cur, slt, bias, res);
  } else if (tier2) {
    hipMemsetAsync(res, 0, (size_t)BT * J * sizeof(float), stream);
    k4b_mfma<<<dim3(4, 16, E), 256, 0, stream>>>(xb, bm, o_idx, o_scr, res);
    k5_final<<<8192, 256, 0, stream>>>(res, o_cnt, bias);
  }
}

// Round 24
// 346.789 us; speedup vs baseline: 1.1007x; 1.0048x over previous
//
#include <hip/hip_runtime.h>
#include <hip/hip_fp16.h>
#include <math.h>

constexpr int BT = 65536;
constexpr int D  = 256;
constexpr int E  = 64;
constexpr int K  = 2048;
constexpr int J  = 512; // 2*D

// d_out layout (floats): res | topk_idx | topk_scores | counts
constexpr size_t OFF_IDX = (size_t)BT * D * 2;       // 33,554,432
constexpr size_t OFF_SCR = OFF_IDX + (size_t)E * K;  // +131,072
constexpr size_t OFF_CNT = OFF_SCR + (size_t)E * K;  // +131,072

// d_ws layout (bytes):
//   xb   bf16[BT][512]        @ 0          (64 MiB)
//   bm   bf16[E][512][512]    @ 64 MiB     (32 MiB)
//   yD   fp16[E*K][512]       @ 96 MiB     (128 MiB)   [tier-1 only]
//   cur  int[BT]              @ 224 MiB    (256 KiB)   [tier-1 only]
//   slot int[BT][32]          @ 224.25 MiB (8 MiB)     [tier-1 only]
constexpr size_t WS_XB    = 0;
constexpr size_t WS_BM    = 67108864;
constexpr size_t WS_YD    = 100663296;
constexpr size_t WS_CUR   = 234881024;
constexpr size_t WS_SLOT  = 235143168;
constexpr size_t WS_NEED1 = 243531776;              // tier-1: full path
constexpr size_t WS_NEED2 = 100663296;              // tier-2 path
constexpr int    SLOT_PAD = 32;

typedef __attribute__((ext_vector_type(8))) short bf16x8;
typedef __attribute__((ext_vector_type(4))) float f32x4;
typedef __attribute__((ext_vector_type(4))) unsigned int u32x4;

__device__ __forceinline__ unsigned short f2bf(float f) {
  unsigned u = __float_as_uint(f);
  u = (u + 0x7FFFu + ((u >> 16) & 1u)) >> 16;  // RTNE
  return (unsigned short)u;
}

__device__ __forceinline__ void gl16(const void* g, void* l) {
  __builtin_amdgcn_global_load_lds(
      (const __attribute__((address_space(1))) unsigned int*)g,
      (__attribute__((address_space(3))) unsigned int*)l, 16, 0, 0);
}

__device__ __forceinline__ unsigned fkey(float s) {
  unsigned u = __float_as_uint(s);
  return (u & 0x80000000u) ? ~u : (u | 0x80000000u);
}

// ---------------------------------------------------------------------------
// K1 (v6 = v5 with full-line Bmat stores): scoresT[e][t] = fp32 dot as ONE
// sequential FMA chain j=0..511 (bit-matches np's sgemm — UNCHANGED).
// 64-token blocks (grid 1024), thread tile 4 tok x 4 exp, b128 LDS reads,
// NT x loads, fused bf16 xb emit.
// Fused Bmat emit: per lane, one n's FOUR consecutive 16B chunks computed
// and stored back-to-back -> each 64B line completes in adjacent stores
// (write-buffer merges; kills the ~9MB partial-line write amplification
// seen in v5's interleaved order). ew reads stay 256B/wave coalesced.
// Values bit-identical to k3b.
// ---------------------------------------------------------------------------
__global__ __launch_bounds__(256)
void k1_scores(const float* __restrict__ x, const float* __restrict__ gw,
               float* __restrict__ scoresT, unsigned short* __restrict__ xbp,
               const float* __restrict__ ew, unsigned short* __restrict__ bmp) {
  __shared__ float xs[64][68];    // 17.4 KB
  __shared__ float gsT[64][68];   // 17.4 KB
  const int t0 = blockIdx.x * 64;
  const int tid = threadIdx.x;
  const int tx = tid & 15;   // token sub-index (4 tokens: a*16+tx)
  const int ty = tid >> 4;   // expert group (4 experts: ty*4+b)
  float acc[4][4] = {};

  for (int kk = 0; kk < 8; ++kk) {
    // ---- stage x (float4 coalesced, NT) + fused bf16 emit
#pragma unroll
    for (int i = 0; i < 4; ++i) {
      int idx = tid + 256 * i;
      int r = idx >> 4, c4 = (idx & 15) * 4;
      f32x4 v = __builtin_nontemporal_load(
          (const f32x4*)(&x[(size_t)(t0 + r) * J + kk * 64 + c4]));
      *(f32x4*)(&xs[r][c4]) = v;
      if (xbp) {
        uint2 u;
        u.x = (unsigned)f2bf(v.x) | ((unsigned)f2bf(v.y) << 16);
        u.y = (unsigned)f2bf(v.z) | ((unsigned)f2bf(v.w) << 16);
        *(uint2*)(&xbp[(size_t)(t0 + r) * J + kk * 64 + c4]) = u;
      }
    }
    // ---- stage gw transposed: gsT[e][j]
#pragma unroll
    for (int i = 0; i < 4; ++i) {
      int idx = tid + 256 * i;
      int r = idx >> 4, c4 = (idx & 15) * 4;   // r = j-local, c4 = expert
      float4 v = *(const float4*)(&gw[(size_t)(kk * 64 + r) * E + c4]);
      gsT[c4][r]     = v.x;
      gsT[c4 + 1][r] = v.y;
      gsT[c4 + 2][r] = v.z;
      gsT[c4 + 3][r] = v.w;
    }
    __syncthreads();
    // ---- compute: j in groups of 4, b128 reads, chain order preserved
#pragma unroll 4
    for (int j = 0; j < 64; j += 4) {
      float4 xv[4], gv[4];
#pragma unroll
      for (int a = 0; a < 4; ++a)
        xv[a] = *(const float4*)(&xs[a * 16 + tx][j]);
#pragma unroll
      for (int b = 0; b < 4; ++b)
        gv[b] = *(const float4*)(&gsT[ty * 4 + b][j]);
#define K1_FMA(COMP)                                                        \
  _Pragma("unroll") for (int a = 0; a < 4; ++a)                             \
    _Pragma("unroll") for (int b = 0; b < 4; ++b)                           \
      acc[a][b] = fmaf(xv[a].COMP, gv[b].COMP, acc[a][b]);
      K1_FMA(x) K1_FMA(y) K1_FMA(z) K1_FMA(w)
#undef K1_FMA
    }
    __syncthreads();
  }

#pragma unroll
  for (int b = 0; b < 4; ++b) {
    int e = ty * 4 + b;
#pragma unroll
    for (int a = 0; a < 4; ++a)
      scoresT[(size_t)e * BT + t0 + a * 16 + tx] = acc[a][b];
  }

  // ---- fused k3b slice (coalesced reads, full-line writes):
  // Bmat[e][n=2f+co][k=2d+ci] = bf16(ew[e][d][f][ci^co] * sign)
  if (bmp) {
    const int be = blockIdx.x >> 4;          // expert
    const int sb = (blockIdx.x & 15) * 4;    // 4-aligned k-octet base
#pragma unroll
    for (int h = 0; h < 2; ++h) {
      int n = (h << 8) + tid;                // 0..511, lane-consecutive
      int f = n >> 1, co = n & 1;
      const float* wb = ew + (((size_t)be * 256) * 256 + f) * 2;
      bf16x8* dst = (bf16x8*)bmp + ((size_t)be << 15) + (size_t)n * 64 + sb;
#pragma unroll
      for (int s2 = 0; s2 < 4; ++s2) {       // 4 consecutive 16B chunks
        int d0 = (sb + s2) * 4;
        union { unsigned short h8[8]; bf16x8 v; } pk;
#pragma unroll
        for (int dd = 0; dd < 4; ++dd) {
          float2 wv = *(const float2*)(wb + (size_t)(d0 + dd) * 512);
          float b0 = co ? wv.y : wv.x;       // ci=0
          float b1 = co ? wv.x : -wv.y;      // ci=1
          pk.h8[dd * 2]     = f2bf(b0);
          pk.h8[dd * 2 + 1] = f2bf(b1);
        }
        dst[s2] = pk.v;                      // 64B line filled back-to-back
      }
    }
  }
}

// ---------------------------------------------------------------------------
// K2a: 12-bit-key histogram, 4 blocks/expert, 8-way privatized LDS, then a
// NON-atomic partial write to parts[bid][4096].
// Fused: zeros o_cnt and cur (256 blocks x 1024 threads == BT exactly).
// ---------------------------------------------------------------------------
__global__ __launch_bounds__(1024)
void k2a_hist(const float* __restrict__ scoresT, unsigned* __restrict__ parts,
              float* __restrict__ o_cnt, int* __restrict__ cur) {
  const int bid = blockIdx.x;          // e*4 + q
  const int tid = threadIdx.x;
  const int g   = bid * 1024 + tid;    // 0 .. BT-1
  o_cnt[g] = 0.0f;
  if (cur) cur[g] = 0;
  __shared__ unsigned h[8][4096];      // 128 KiB, 8-way privatization
  for (int i = tid; i < 8 * 4096; i += 1024) ((unsigned*)h)[i] = 0u;
  __syncthreads();
  const int copy = tid >> 7;           // 2 waves share a copy
  const float4* src = (const float4*)(scoresT + ((size_t)bid << 14));
#pragma unroll
  for (int it = 0; it < 4; ++it) {
    float4 v = src[it * 1024 + tid];
    atomicAdd(&h[copy][fkey(v.x) >> 20], 1u);
    atomicAdd(&h[copy][fkey(v.y) >> 20], 1u);
    atomicAdd(&h[copy][fkey(v.z) >> 20], 1u);
    atomicAdd(&h[copy][fkey(v.w) >> 20], 1u);
  }
  __syncthreads();
  unsigned* dst = parts + ((size_t)bid << 12);
  for (int j = tid; j < 4096; j += 1024) {
    unsigned s = 0;
#pragma unroll
    for (int c = 0; c < 8; ++c) s += h[c][j];
    dst[j] = s;
  }
}

// ---------------------------------------------------------------------------
// K2b: per-expert descending scan over summed parts -> 12-bit bucket of the
// rank-K key. Fused: zeros ccnt[e].
// ---------------------------------------------------------------------------
__global__ __launch_bounds__(256)
void k2b_scan(const unsigned* __restrict__ parts, unsigned* __restrict__ thr12,
              int* __restrict__ ccnt) {
  const int e = blockIdx.x;
  const unsigned* p = parts + ((size_t)e << 14);  // 4 parts x 4096
  __shared__ unsigned chs[256];
  const int tid = threadIdx.x;
  if (tid == 0) ccnt[e] = 0;
  const int lo = 4095 - tid * 16 - 15;  // chunk tid covers [lo, lo+15] desc
  unsigned s = 0;
  for (int j = 0; j < 16; ++j) {
    int b = lo + j;
    s += p[b] + p[4096 + b] + p[8192 + b] + p[12288 + b];
  }
  chs[tid] = s;
  __syncthreads();
  if (tid == 0) {
    unsigned cum = 0; int c = 0;
    for (; c < 255; ++c) {
      if (cum + chs[c] >= (unsigned)K) break;
      cum += chs[c];
    }
    int vb = 4095 - c * 16;
    unsigned b = 0;
    for (int j = 0; j < 16; ++j) {
      int bb = vb - j;
      cum += p[bb] + p[4096 + bb] + p[8192 + bb] + p[12288 + bb];
      if (cum >= (unsigned)K) { b = (unsigned)bb; break; }
    }
    thr12[e] = b;
  }
}

// ---------------------------------------------------------------------------
// K2c: parallel collect, 4 blocks/expert. LDS-local cursor; ONE global
// atomic per block reserves a segment of cand[e]; coalesced flush.
// NT loads: k2c is the LAST reader of scoresT.
// ---------------------------------------------------------------------------
__global__ __launch_bounds__(1024)
void k2c_collect(const float* __restrict__ scoresT,
                 const unsigned* __restrict__ thr12,
                 unsigned long long* __restrict__ cand,
                 int* __restrict__ ccnt) {
  const int bid = blockIdx.x;  // e*4 + q
  const int e = bid >> 2;
  const unsigned bthr = thr12[e] << 20;
  const float* row = scoresT + ((size_t)bid << 14);
  const unsigned ibase = (unsigned)(bid & 3) << 14;
  __shared__ int sh_n, sh_base;
  __shared__ unsigned long long lkeys[4096];
  const int tid = threadIdx.x;
  if (tid == 0) sh_n = 0;
  __syncthreads();
  for (int i = tid; i < 16384; i += 1024) {
    float sv = __builtin_nontemporal_load(&row[i]);
    unsigned u = fkey(sv);
    if (u >= bthr) {
      int pos = atomicAdd(&sh_n, 1);   // LDS atomic
      if (pos < 4096)
        lkeys[pos] =
            ((unsigned long long)u << 32) | (unsigned)(~(ibase + i));
    }
  }
  __syncthreads();
  int n = sh_n; if (n > 4096) n = 4096;
  if (tid == 0) sh_base = atomicAdd(&ccnt[e], n);  // one global atomic/block
  __syncthreads();
  const int base = sh_base;
  for (int i = tid; i < n; i += 1024)
    if (base + i < 4096) cand[((size_t)e << 12) + base + i] = lkeys[i];
}

// ---------------------------------------------------------------------------
// K2d: per-expert bitonic sort of candidates (score desc, idx asc) + output
// tail. Comparator network is order-canonical -> bit-identical results.
// NT loads for cand (read-once).
// ---------------------------------------------------------------------------
__global__ __launch_bounds__(1024)
void k2d_sort(const unsigned long long* __restrict__ cand,
              const int* __restrict__ ccnt,
              float* __restrict__ o_idx, float* __restrict__ o_scr,
              float* __restrict__ o_cnt,
              int* __restrict__ cur, int* __restrict__ slots) {
  const int e = blockIdx.x;
  __shared__ unsigned long long keys[4096];
  const int tid = threadIdx.x;
  int n = ccnt[e]; if (n > 4096) n = 4096;
  for (int i = tid; i < 4096; i += 1024)
    keys[i] = (i < n)
        ? __builtin_nontemporal_load(&cand[((size_t)e << 12) + i])
        : 0ull;
  __syncthreads();
  for (int kk = 2; kk <= 4096; kk <<= 1) {
    for (int j = kk >> 1; j > 0; j >>= 1) {
      for (int i = tid; i < 4096; i += 1024) {
        int ij = i ^ j;
        if (ij > i) {
          bool up = ((i & kk) == 0);
          unsigned long long a = keys[i], b = keys[ij];
          if ((a < b) == up) { keys[i] = b; keys[ij] = a; }
        }
      }
      __syncthreads();
    }
  }
  for (int r = tid; r < K; r += 1024) {
    unsigned long long kv = keys[r];
    unsigned u = (unsigned)(kv >> 32);
    unsigned idx = ~((unsigned)kv);
    float s = __uint_as_float((u & 0x80000000u) ? (u ^ 0x80000000u) : ~u);
    o_idx[(size_t)e * K + r] = (float)idx;
    o_scr[(size_t)e * K + r] = s;
    atomicAdd(&o_cnt[idx], 1.0f);
    if (slots) {
      int pos = atomicAdd(&cur[idx], 1);
      if (pos < SLOT_PAD) slots[(size_t)idx * SLOT_PAD + pos] = e * K + r;
    }
  }
}

// ---------------------------------------------------------------------------
// K4c (tier-1, v8): MFMA bf16 GEMM, dense fp16 output (NO atomics).
// 128x128 tile, BK=64, 2-phase double-buffered LDS, setprio(1) around MFMA
// cluster (T5, +13% measured), NT yD stores (write-once stream).
// ---------------------------------------------------------------------------
__global__ __launch_bounds__(256)
void k4c_mfma(const unsigned short* __restrict__ xb,
              const unsigned short* __restrict__ bm,
              const float* __restrict__ o_idx, const float* __restrict__ o_scr,
              unsigned short* __restrict__ yD) {
  const int bid = blockIdx.x;
  const int xcd = bid & 7;
  const int s   = bid >> 3;
  const int fn  = s & 3;
  const int km  = (s >> 2) & 15;
  const int e   = xcd + ((s >> 6) << 3);

  // sh: A dbuf = sh + cb*8192 (each 128 rows x 64 shorts);
  //     B dbuf = sh + 16384 + cb*8192. Pk overlay @0 (17408 shorts).
  __shared__ __align__(16) unsigned short sh[32768];
  __shared__ int   tIdx[128];
  __shared__ float wRow[128];
  const int tid = threadIdx.x;
  if (tid < 128) {
    size_t gi = (size_t)e * K + km * 128 + tid;
    tIdx[tid] = (int)o_idx[gi];
    wRow[tid] = o_scr[gi];
  }
  __syncthreads();

  const int lane = tid & 63;
  const int w    = tid >> 6;
  const int wr   = (w & 1) * 64;
  const int wc   = (w >> 1) * 64;
  const int l15  = lane & 15, l4 = lane >> 4;
  const int ls   = lane & 7, lr = lane >> 3;
  const int gch  = ls ^ lr;  // pre-swizzled source chunk (row&7 == lr)

  // per-lane global source bases and LDS dest offsets (shorts) per row-octet
  const char* aSrc[4];
  const char* bSrc[4];
  int dstOff[4];
#pragma unroll
  for (int i = 0; i < 4; ++i) {
    int r = w * 32 + i * 8 + lr;
    aSrc[i] = (const char*)xb + (size_t)tIdx[r] * 1024 + gch * 16;
    bSrc[i] = (const char*)bm + ((size_t)e * 512 + fn * 128 + r) * 1024 +
              gch * 16;
    dstOff[i] = (w * 32 + i * 8) * 64 + lane * 8;
  }

  f32x4 acc[4][4];
#pragma unroll
  for (int m = 0; m < 4; ++m)
#pragma unroll
    for (int n = 0; n < 4; ++n) acc[m][n] = (f32x4){0.f, 0.f, 0.f, 0.f};

  // prologue: K-step 0 into buffer 0
#pragma unroll
  for (int i = 0; i < 4; ++i) {
    gl16(aSrc[i], sh + dstOff[i]);
    gl16(bSrc[i], sh + 16384 + dstOff[i]);
  }

#pragma unroll
  for (int t = 0; t < 8; ++t) {
    const int cb = t & 1;
    __syncthreads();  // drains vmcnt -> buffer cb ready
    if (t < 7) {      // stage next tile into cb^1 while computing cb
      const int nxt = (cb ^ 1) * 8192;
#pragma unroll
      for (int i = 0; i < 4; ++i) {
        gl16(aSrc[i] + (t + 1) * 128, sh + nxt + dstOff[i]);
        gl16(bSrc[i] + (t + 1) * 128, sh + 16384 + nxt + dstOff[i]);
      }
    }
    const unsigned short* Ab = sh + cb * 8192;
    const unsigned short* Bb = sh + 16384 + cb * 8192;
#pragma unroll
    for (int kk2 = 0; kk2 < 2; ++kk2) {
      bf16x8 af[4], bfr[4];
#pragma unroll
      for (int m = 0; m < 4; ++m) {
        int r = wr + m * 16 + l15;
        int sw = (kk2 * 4 + l4) ^ (r & 7);
        af[m] = *(const bf16x8*)(&Ab[r * 64 + sw * 8]);
      }
#pragma unroll
      for (int n = 0; n < 4; ++n) {
        int cl = wc + n * 16 + l15;
        int sw = (kk2 * 4 + l4) ^ (cl & 7);
        bfr[n] = *(const bf16x8*)(&Bb[cl * 64 + sw * 8]);
      }
      __builtin_amdgcn_s_setprio(1);
#pragma unroll
      for (int m = 0; m < 4; ++m)
#pragma unroll
        for (int n = 0; n < 4; ++n)
          acc[m][n] = __builtin_amdgcn_mfma_f32_16x16x32_bf16(
              af[m], bfr[n], acc[m][n], 0, 0, 0);
      __builtin_amdgcn_s_setprio(0);
    }
  }

  // epilogue: weight, fp16-pack via padded-LDS repack (stride 136), NT store
  __syncthreads();
  unsigned short* Pk = sh;  // 128 x 136 = 17408 shorts (fits in 32768)
#pragma unroll
  for (int m = 0; m < 4; ++m) {
#pragma unroll
    for (int q = 0; q < 4; ++q) {
      int row = wr + m * 16 + l4 * 4 + q;
      float wv = wRow[row];
#pragma unroll
      for (int n = 0; n < 4; ++n) {
        int col = wc + n * 16 + l15;
        Pk[row * 136 + col] =
            __half_as_ushort(__float2half(acc[m][n][q] * wv));
      }
    }
  }
  __syncthreads();
  const size_t rowBase = (size_t)e * K + km * 128;
#pragma unroll
  for (int i = 0; i < 8; ++i) {
    int c2 = tid + 256 * i;
    int row = c2 >> 4, ch = c2 & 15;
    u32x4 v = *(const u32x4*)(&Pk[row * 136 + ch * 8]);
    __builtin_nontemporal_store(
        v, (u32x4*)(yD + (rowBase + row) * 512 + fn * 128 + ch * 8));
  }
}

// ---------------------------------------------------------------------------
// K5g (tier-1): per-token gather-finalize (one wave per token).
// NT loads for yD (read-once) and NT stores for res (write-once).
// ---------------------------------------------------------------------------
__global__ __launch_bounds__(256)
void k5g(const unsigned short* __restrict__ yD, const int* __restrict__ cur,
         const int* __restrict__ slots, const float* __restrict__ bias,
         float* __restrict__ res) {
  const int t    = blockIdx.x * 4 + (threadIdx.x >> 6);
  const int lane = threadIdx.x & 63;
  const int nc   = cur[t];
  const int ncc  = nc < SLOT_PAD ? nc : SLOT_PAD;
  float acc[8] = {};
  const int* sl = slots + (size_t)t * SLOT_PAD;
  for (int c = 0; c < ncc; ++c) {
    int slot = sl[c];
    union { u32x4 v; unsigned short h[8]; } U;
    U.v = __builtin_nontemporal_load(
        (const u32x4*)(yD + (size_t)slot * 512 + lane * 8));
#pragma unroll
    for (int j = 0; j < 8; ++j)
      acc[j] += __half2float(__ushort_as_half(U.h[j]));
  }
  const float inv = 1.0f / fmaxf((float)nc, 1.0f);
  float4 b4 = *(const float4*)(bias + lane * 4);
  const float* bp = (const float*)&b4;
  const float is2 = 0.70710678118654752f;
  float r8[8];
#pragma unroll
  for (int j = 0; j < 8; ++j) {
    float h = acc[j] * inv + bp[j >> 1];
    r8[j] = 0.5f * h * (1.0f + erff(h * is2));
  }
  float* dst = res + (size_t)t * J + lane * 8;
  f32x4 lo = (f32x4){r8[0], r8[1], r8[2], r8[3]};
  f32x4 hi = (f32x4){r8[4], r8[5], r8[6], r8[7]};
  __builtin_nontemporal_store(lo, (f32x4*)dst);
  __builtin_nontemporal_store(hi, (f32x4*)(dst + 4));
}

// ---------------------------------------------------------------------------
// K3b (tier-2 fallback only): Bmat[e][n][k] = bf16( ew * sign ).
// ---------------------------------------------------------------------------
__global__ __launch_bounds__(256)
void k3b_bmat(const float* __restrict__ ew, unsigned short* __restrict__ bm) {
  int id = blockIdx.x * 256 + threadIdx.x;
  int sub = id & 63;
  int ng  = id >> 6;
  int e   = ng >> 9;
  int n   = ng & 511;
  int f   = n >> 1, co = n & 1;
  int d0  = sub * 4;
  const float* wb = ew + (((size_t)e * 256) * 256 + f) * 2;
  union { unsigned short h[8]; bf16x8 v; } pk;
#pragma unroll
  for (int dd = 0; dd < 4; ++dd) {
    float2 wv = *(const float2*)(wb + (size_t)(d0 + dd) * 512);
    float b0 = co ? wv.y : wv.x;
    float b1 = co ? wv.x : -wv.y;
    pk.h[dd * 2]     = f2bf(b0);
    pk.h[dd * 2 + 1] = f2bf(b1);
  }
  ((bf16x8*)bm)[id] = pk.v;
}

// ---------------------------------------------------------------------------
// K4b (tier-2 fallback): atomic-scatter MFMA GEMM (round-7 verified).
// ---------------------------------------------------------------------------
__global__ __launch_bounds__(256)
void k4b_mfma(const unsigned short* __restrict__ xb,
              const unsigned short* __restrict__ bm,
              const float* __restrict__ o_idx, const float* __restrict__ o_scr,
              float* __restrict__ out) {
  const int e  = blockIdx.z;
  const int km = blockIdx.y;
  const int fn = blockIdx.x;
  __shared__ __align__(16) unsigned short As[128 * 64];
  __shared__ __align__(16) unsigned short Bs[128 * 64];
  __shared__ int   tIdx[128];
  __shared__ float wRow[128];
  const int tid = threadIdx.x;
  if (tid < 128) {
    size_t gi = (size_t)e * K + km * 128 + tid;
    tIdx[tid] = (int)o_idx[gi];
    wRow[tid] = o_scr[gi];
  }
  __syncthreads();

  const int lane = tid & 63;
  const int w    = tid >> 6;
  const int wr   = (w & 1) * 64;
  const int wc   = (w >> 1) * 64;
  const int l15  = lane & 15, l4 = lane >> 4;
  const int ls   = lane & 7, lr = lane >> 3;
  const int gch  = ls ^ lr;

  const char* aSrc[4];
  const char* bSrc[4];
  unsigned short* aDst[4];
  unsigned short* bDst[4];
#pragma unroll
  for (int i = 0; i < 4; ++i) {
    int r = w * 32 + i * 8 + lr;
    aSrc[i] = (const char*)xb + (size_t)tIdx[r] * 1024 + gch * 16;
    bSrc[i] = (const char*)bm + ((size_t)e * 512 + fn * 128 + r) * 1024 +
              gch * 16;
    aDst[i] = As + (w * 32 + i * 8) * 64 + lane * 8;
    bDst[i] = Bs + (w * 32 + i * 8) * 64 + lane * 8;
  }

  f32x4 acc[4][4];
#pragma unroll
  for (int m = 0; m < 4; ++m)
#pragma unroll
    for (int n = 0; n < 4; ++n) acc[m][n] = (f32x4){0.f, 0.f, 0.f, 0.f};

  for (int kk = 0; kk < J; kk += 64) {
#pragma unroll
    for (int i = 0; i < 4; ++i) {
      gl16(aSrc[i] + kk * 2, aDst[i]);
      gl16(bSrc[i] + kk * 2, bDst[i]);
    }
    __syncthreads();
#pragma unroll
    for (int kk2 = 0; kk2 < 2; ++kk2) {
      bf16x8 af[4], bfr[4];
#pragma unroll
      for (int m = 0; m < 4; ++m) {
        int r = wr + m * 16 + l15;
        int s = (kk2 * 4 + l4) ^ (r & 7);
        af[m] = *(const bf16x8*)(&As[r * 64 + s * 8]);
      }
#pragma unroll
      for (int n = 0; n < 4; ++n) {
        int cl = wc + n * 16 + l15;
        int s = (kk2 * 4 + l4) ^ (cl & 7);
        bfr[n] = *(const bf16x8*)(&Bs[cl * 64 + s * 8]);
      }
#pragma unroll
      for (int m = 0; m < 4; ++m)
#pragma unroll
        for (int n = 0; n < 4; ++n)
          acc[m][n] = __builtin_amdgcn_mfma_f32_16x16x32_bf16(
              af[m], bfr[n], acc[m][n], 0, 0, 0);
    }
    __syncthreads();
  }

#pragma unroll
  for (int m = 0; m < 4; ++m) {
#pragma unroll
    for (int q = 0; q < 4; ++q) {
      int rl = wr + m * 16 + l4 * 4 + q;
      int t = tIdx[rl];
      float wv = wRow[rl];
      float* dst = out + (size_t)t * J + fn * 128 + wc + l15;
#pragma unroll
      for (int n = 0; n < 4; ++n)
        atomicAdd(dst + n * 16, acc[m][n][q] * wv);
    }
  }
}

// ---------------------------------------------------------------------------
// K5 (tier-2 fallback): res = gelu(out/max(cnt,1)+bias), in place.
// ---------------------------------------------------------------------------
__global__ __launch_bounds__(256)
void k5_final(float* __restrict__ res, const float* __restrict__ cnt,
              const float* __restrict__ bias) {
  const int total4 = BT * J / 4;
  for (int i = blockIdx.x * blockDim.x + threadIdx.x; i < total4;
       i += gridDim.x * blockDim.x) {
    float4 v = reinterpret_cast<float4*>(res)[i];
    int base = i << 2;
    int t = base >> 9;
    int col = base & 511;
    float inv = 1.0f / fmaxf(cnt[t], 1.0f);
    int f0 = col >> 1;
    float b0 = bias[f0], b1 = bias[f0 + 1];
    float h0 = v.x * inv + b0;
    float h1 = v.y * inv + b0;
    float h2 = v.z * inv + b1;
    float h3 = v.w * inv + b1;
    const float is2 = 0.70710678118654752f;
    v.x = 0.5f * h0 * (1.0f + erff(h0 * is2));
    v.y = 0.5f * h1 * (1.0f + erff(h1 * is2));
    v.z = 0.5f * h2 * (1.0f + erff(h2 * is2));
    v.w = 0.5f * h3 * (1.0f + erff(h3 * is2));
    reinterpret_cast<float4*>(res)[i] = v;
  }
}

// ---------------------------------------------------------------------------
extern "C" void kernel_launch(void* const* d_in, const int* in_sizes, int n_in,
                              void* d_out, int out_size, void* d_ws,
                              size_t ws_size, hipStream_t stream) {
  const float* x    = (const float*)d_in[0];
  const float* gw   = (const float*)d_in[1];
  const float* ew   = (const float*)d_in[2];
  const float* bias = (const float*)d_in[3];

  float* out_f = (float*)d_out;
  float* res   = out_f;
  float* o_idx = out_f + OFF_IDX;
  float* o_scr = out_f + OFF_SCR;
  float* o_cnt = out_f + OFF_CNT;

  // Borrowed regions inside res (all rewritten later by k5g/k5):
  //   scoresT @ 0 (16.8 MB) | parts @ 32 MB | thr12 @ 36 MB |
  //   cand @ 48 MB (2 MB) | ccnt @ 52 MB
  float*              scoresT = res;
  unsigned*           parts   = (unsigned*)((char*)res + (size_t)32 * 1024 * 1024);
  unsigned*           thr12   = (unsigned*)((char*)res + (size_t)36 * 1024 * 1024);
  unsigned long long* cand    = (unsigned long long*)((char*)res + (size_t)48 * 1024 * 1024);
  int*                ccnt    = (int*)((char*)res + (size_t)52 * 1024 * 1024);

  unsigned short* xb  = (unsigned short*)((char*)d_ws + WS_XB);
  unsigned short* bm  = (unsigned short*)((char*)d_ws + WS_BM);
  unsigned short* yD  = (unsigned short*)((char*)d_ws + WS_YD);
  int*            cur = (int*)((char*)d_ws + WS_CUR);
  int*            slt = (int*)((char*)d_ws + WS_SLOT);

  const bool tier1 = (ws_size >= WS_NEED1);
  const bool tier2 = (ws_size >= WS_NEED2);

  // k3b fused into k1 (tier-1/2); standalone launch no longer needed.
  k1_scores<<<BT / 64, 256, 0, stream>>>(x, gw, scoresT,
                                         tier2 ? xb : nullptr, ew,
                                         tier2 ? bm : nullptr);
  k2a_hist<<<E * 4, 1024, 0, stream>>>(scoresT, parts, o_cnt,
                                       tier1 ? cur : nullptr);
  k2b_scan<<<E, 256, 0, stream>>>(parts, thr12, ccnt);
  k2c_collect<<<E * 4, 1024, 0, stream>>>(scoresT, thr12, cand, ccnt);
  k2d_sort<<<E, 1024, 0, stream>>>(cand, ccnt, o_idx, o_scr, o_cnt,
                                   tier1 ? cur : nullptr,
                                   tier1 ? slt : nullptr);
  if (tier1) {
    k4c_mfma<<<4096, 256, 0, stream>>>(xb, bm, o_idx, o_scr, yD);
    k5g<<<BT / 4, 256, 0, stream>>>(yD, cur, slt, bias, res);
  } else if (tier2) {
    hipMemsetAsync(res, 0, (size_t)BT * J * sizeof(float), stream);
    k4b_mfma<<<dim3(4, 16, E), 256, 0, stream>>>(xb, bm, o_idx, o_scr, res);
    k5_final<<<8192, 256, 0, stream>>>(res, o_cnt, bias);
  }
}